// Round 1
// baseline (1628.691 us; speedup 1.0000x reference)
//
#include <hip/hip_runtime.h>
#include <math.h>

#define DIN 64

// ---------------- CSR construction ----------------

__global__ void hist_kernel(const int* __restrict__ col, int* __restrict__ cnt, int E) {
    int i = blockIdx.x * blockDim.x + threadIdx.x;
    int stride = gridDim.x * blockDim.x;
    for (; i < E; i += stride) atomicAdd(&cnt[col[i]], 1);
}

__global__ void dinv_kernel(const int* __restrict__ cnt, float* __restrict__ dinv, int N) {
    int i = blockIdx.x * blockDim.x + threadIdx.x;
    if (i < N) {
        int c = cnt[i];
        dinv[i] = (c > 0) ? rsqrtf((float)c) : 0.0f;
    }
}

// Single-block two-phase scan: 1024 threads, each owns a contiguous chunk.
__global__ void scan_kernel(const int* __restrict__ cnt, int* __restrict__ rowptr, int N) {
    __shared__ int sm[1024];
    int tid = threadIdx.x;
    int C = (N + 1023) / 1024;
    int start = tid * C;
    int end = min(start + C, N);
    int s = 0;
    for (int i = start; i < end; ++i) s += cnt[i];
    sm[tid] = s;
    __syncthreads();
    for (int off = 1; off < 1024; off <<= 1) {
        int add = (tid >= off) ? sm[tid - off] : 0;
        __syncthreads();
        sm[tid] += add;
        __syncthreads();
    }
    int run = sm[tid] - s;  // exclusive prefix
    for (int i = start; i < end; ++i) { rowptr[i] = run; run += cnt[i]; }
    if (tid == 1023) rowptr[N] = sm[1023];
}

__global__ void fill_kernel(const int* __restrict__ row, const int* __restrict__ col,
                            const int* __restrict__ rowptr, int* __restrict__ cursor,
                            const float* __restrict__ dinv,
                            int* __restrict__ src, float* __restrict__ w, int E) {
    int i = blockIdx.x * blockDim.x + threadIdx.x;
    int stride = gridDim.x * blockDim.x;
    for (; i < E; i += stride) {
        int c = col[i];
        int r = row[i];
        int p = rowptr[c] + atomicAdd(&cursor[c], 1);
        src[p] = r;
        w[p] = dinv[r] * dinv[c];
    }
}

// ---------------- propagation: one wave per node, lane = feature ----------------

__global__ void prop_kernel(const int* __restrict__ rowptr, const int* __restrict__ src,
                            const float* __restrict__ w, const float* __restrict__ h,
                            float* __restrict__ out, int N) {
    int gid = blockIdx.x * blockDim.x + threadIdx.x;
    int node = gid >> 6;
    int lane = gid & 63;
    if (node >= N) return;
    int beg = rowptr[node], end = rowptr[node + 1];
    float acc = 0.0f;
    for (int j = beg; j < end; ++j) {
        int s = src[j];
        float ww = w[j];
        acc = fmaf(ww, h[(size_t)s * DIN + lane], acc);
    }
    out[(size_t)node * DIN + lane] = acc;
}

// ---------------- small dense matmul: out[N x DOUT] = H[N x 64] @ W[64 x DOUT] ----------------
// MODE 0: out = H@W     MODE 1: out = accin + H@W     MODE 2: out = relu(accin + H@W + bias)

template <int DOUT, int MODE>
__global__ void mm_kernel(const float* __restrict__ H, const float* __restrict__ W,
                          const float* __restrict__ bias, const float* __restrict__ accin,
                          float* __restrict__ out, int N) {
    __shared__ float Ws[DIN][DOUT];
    __shared__ float Hs[16][DIN + 1];
    int tid = threadIdx.x;
    int row0 = blockIdx.x * 16;
    for (int i = tid; i < DIN * DOUT; i += 256) Ws[i / DOUT][i % DOUT] = W[i];
    for (int i = tid; i < 16 * DIN; i += 256) {
        int r = i >> 6, k = i & 63;
        int gr = row0 + r;
        Hs[r][k] = (gr < N) ? H[(size_t)gr * DIN + k] : 0.0f;
    }
    __syncthreads();
    for (int idx = tid; idx < 16 * DOUT; idx += 256) {
        int r = idx / DOUT, c = idx - r * DOUT;
        int gr = row0 + r;
        if (gr >= N) continue;
        float s = 0.0f;
#pragma unroll
        for (int k = 0; k < DIN; ++k) s = fmaf(Hs[r][k], Ws[k][c], s);
        size_t o = (size_t)gr * DOUT + c;
        if (MODE == 0) {
            out[o] = s;
        } else if (MODE == 1) {
            out[o] = accin[o] + s;
        } else {
            float v = accin[o] + s + bias[c];
            out[o] = v > 0.0f ? v : 0.0f;
        }
    }
}

// ---------------- log_softmax over rows of 40 (one wave per row) ----------------

__global__ void lsm_kernel(float* __restrict__ out, const float* __restrict__ bias, int N) {
    int gid = blockIdx.x * blockDim.x + threadIdx.x;
    int row = gid >> 6;
    int lane = gid & 63;
    if (row >= N) return;
    float v = (lane < 40) ? out[(size_t)row * 40 + lane] + bias[lane] : -INFINITY;
    float m = v;
    for (int off = 32; off > 0; off >>= 1) m = fmaxf(m, __shfl_xor(m, off, 64));
    float e = (lane < 40) ? expf(v - m) : 0.0f;
    float ssum = e;
    for (int off = 32; off > 0; off >>= 1) ssum += __shfl_xor(ssum, off, 64);
    if (lane < 40) out[(size_t)row * 40 + lane] = v - m - logf(ssum);
}

// ---------------- launch ----------------

extern "C" void kernel_launch(void* const* d_in, const int* in_sizes, int n_in,
                              void* d_out, int out_size, void* d_ws, size_t ws_size,
                              hipStream_t stream) {
    const float* x  = (const float*)d_in[0];
    const int*   ei = (const int*)d_in[1];
    const float* W1 = (const float*)d_in[2];
    const float* b1 = (const float*)d_in[3];
    const float* W2 = (const float*)d_in[4];
    const float* b2 = (const float*)d_in[5];

    int N = in_sizes[0] / DIN;
    int E = in_sizes[1] / 2;
    const int* rowv = ei;       // edge_index[0] = source of message
    const int* colv = ei + E;   // edge_index[1] = destination (segment id)

    char* p = (char*)d_ws;
    auto alloc = [&](size_t bytes) {
        char* q = p;
        p += (bytes + 255) & ~(size_t)255;
        return q;
    };
    int*   cnt    = (int*)alloc((size_t)N * 4);
    int*   cursor = (int*)alloc((size_t)N * 4);
    int*   rowptr = (int*)alloc((size_t)(N + 1) * 4);
    float* dinv   = (float*)alloc((size_t)N * 4);
    int*   src    = (int*)alloc((size_t)E * 4);
    float* w      = (float*)alloc((size_t)E * 4);
    float* t1     = (float*)alloc((size_t)N * DIN * 4);
    float* t2     = (float*)alloc((size_t)N * DIN * 4);
    float* acc    = (float*)alloc((size_t)N * DIN * 4);
    float* outp   = (float*)d_out;

    hipMemsetAsync(cnt, 0, (size_t)N * 4, stream);
    hipMemsetAsync(cursor, 0, (size_t)N * 4, stream);

    const int tpb = 256;
    hist_kernel<<<1024, tpb, 0, stream>>>(colv, cnt, E);
    dinv_kernel<<<(N + tpb - 1) / tpb, tpb, 0, stream>>>(cnt, dinv, N);
    scan_kernel<<<1, 1024, 0, stream>>>(cnt, rowptr, N);
    fill_kernel<<<1024, tpb, 0, stream>>>(rowv, colv, rowptr, cursor, dinv, src, w, E);

    int propBlocks = (N * 64 + tpb - 1) / tpb;   // one wave (64 lanes) per node
    int mmBlocks = (N + 15) / 16;

    // ---- layer 1: acc = x@W1[0] + sum_k prop^k(x)@W1[k]; h = relu(acc + b1) -> t2
    mm_kernel<64, 0><<<mmBlocks, 256, 0, stream>>>(x, W1 + 0 * 64 * 64, nullptr, nullptr, acc, N);
    prop_kernel<<<propBlocks, tpb, 0, stream>>>(rowptr, src, w, x, t1, N);
    mm_kernel<64, 1><<<mmBlocks, 256, 0, stream>>>(t1, W1 + 1 * 64 * 64, nullptr, acc, acc, N);
    prop_kernel<<<propBlocks, tpb, 0, stream>>>(rowptr, src, w, t1, t2, N);
    mm_kernel<64, 1><<<mmBlocks, 256, 0, stream>>>(t2, W1 + 2 * 64 * 64, nullptr, acc, acc, N);
    prop_kernel<<<propBlocks, tpb, 0, stream>>>(rowptr, src, w, t2, t1, N);
    mm_kernel<64, 2><<<mmBlocks, 256, 0, stream>>>(t1, W1 + 3 * 64 * 64, b1, acc, t2, N);

    // ---- layer 2: out = h@W2[0] + sum_k prop^k(h)@W2[k]  (h = t2), bias folded into lsm
    mm_kernel<40, 0><<<mmBlocks, 256, 0, stream>>>(t2, W2 + 0 * 64 * 40, nullptr, nullptr, outp, N);
    prop_kernel<<<propBlocks, tpb, 0, stream>>>(rowptr, src, w, t2, t1, N);
    mm_kernel<40, 1><<<mmBlocks, 256, 0, stream>>>(t1, W2 + 1 * 64 * 40, nullptr, outp, outp, N);
    prop_kernel<<<propBlocks, tpb, 0, stream>>>(rowptr, src, w, t1, t2, N);
    mm_kernel<40, 1><<<mmBlocks, 256, 0, stream>>>(t2, W2 + 2 * 64 * 40, nullptr, outp, outp, N);
    prop_kernel<<<propBlocks, tpb, 0, stream>>>(rowptr, src, w, t2, t1, N);
    mm_kernel<40, 1><<<mmBlocks, 256, 0, stream>>>(t1, W2 + 3 * 64 * 40, nullptr, outp, outp, N);

    lsm_kernel<<<propBlocks, tpb, 0, stream>>>(outp, b2, N);
}

// Round 2
// 963.648 us; speedup vs baseline: 1.6901x; 1.6901x over previous
//
#include <hip/hip_runtime.h>
#include <math.h>

#define DIN 64

// ---------------- CSR construction ----------------

__global__ void hist_kernel(const int* __restrict__ col, int* __restrict__ cnt, int E) {
    int i = blockIdx.x * blockDim.x + threadIdx.x;
    int stride = gridDim.x * blockDim.x;
    for (; i < E; i += stride) atomicAdd(&cnt[col[i]], 1);
}

__global__ void dinv_kernel(const int* __restrict__ cnt, float* __restrict__ dinv, int N) {
    int i = blockIdx.x * blockDim.x + threadIdx.x;
    if (i < N) {
        int c = cnt[i];
        dinv[i] = (c > 0) ? rsqrtf((float)c) : 0.0f;
    }
}

// ---- 3-phase exclusive scan of cnt[N] -> rowptr[N+1] ----
// Phase A: per-block (1024 elems) sums. Phase B: scan block sums (<=1024 blocks).
// Phase C: per-block local scan + offset.

__global__ void scanA_kernel(const int* __restrict__ cnt, int* __restrict__ bsum, int N) {
    __shared__ int sm[256];
    int tid = threadIdx.x;
    int base = blockIdx.x * 1024 + tid * 4;
    int s = 0;
#pragma unroll
    for (int i = 0; i < 4; ++i) {
        int idx = base + i;
        if (idx < N) s += cnt[idx];
    }
    sm[tid] = s;
    __syncthreads();
    for (int off = 128; off > 0; off >>= 1) {
        if (tid < off) sm[tid] += sm[tid + off];
        __syncthreads();
    }
    if (tid == 0) bsum[blockIdx.x] = sm[0];
}

__global__ void scanB_kernel(const int* __restrict__ bsum, int* __restrict__ boff,
                             int* __restrict__ rowptr, int B, int N) {
    __shared__ int sm[1024];
    int tid = threadIdx.x;
    int v = (tid < B) ? bsum[tid] : 0;
    sm[tid] = v;
    __syncthreads();
    for (int off = 1; off < 1024; off <<= 1) {
        int add = (tid >= off) ? sm[tid - off] : 0;
        __syncthreads();
        sm[tid] += add;
        __syncthreads();
    }
    if (tid < B) boff[tid] = sm[tid] - v;  // exclusive
    if (tid == 1023) rowptr[N] = sm[1023]; // total = E
}

__global__ void scanC_kernel(const int* __restrict__ cnt, const int* __restrict__ boff,
                             int* __restrict__ rowptr, int N) {
    __shared__ int sm[256];
    int tid = threadIdx.x;
    int base = blockIdx.x * 1024 + tid * 4;
    int v[4];
    int s = 0;
#pragma unroll
    for (int i = 0; i < 4; ++i) {
        int idx = base + i;
        v[i] = (idx < N) ? cnt[idx] : 0;
        s += v[i];
    }
    sm[tid] = s;
    __syncthreads();
    for (int off = 1; off < 256; off <<= 1) {
        int add = (tid >= off) ? sm[tid - off] : 0;
        __syncthreads();
        sm[tid] += add;
        __syncthreads();
    }
    int run = boff[blockIdx.x] + sm[tid] - s;  // exclusive prefix for this thread
#pragma unroll
    for (int i = 0; i < 4; ++i) {
        int idx = base + i;
        if (idx < N) rowptr[idx] = run;
        run += v[i];
    }
}

__global__ void fill_kernel(const int* __restrict__ row, const int* __restrict__ col,
                            const int* __restrict__ rowptr, int* __restrict__ cursor,
                            const float* __restrict__ dinv,
                            int* __restrict__ src, float* __restrict__ w, int E) {
    int i = blockIdx.x * blockDim.x + threadIdx.x;
    int stride = gridDim.x * blockDim.x;
    for (; i < E; i += stride) {
        int c = col[i];
        int r = row[i];
        int p = rowptr[c] + atomicAdd(&cursor[c], 1);
        src[p] = r;
        w[p] = dinv[r] * dinv[c];
    }
}

// ---------------- propagation: one wave per node, lane = feature ----------------
// Scalarized edge metadata (readfirstlane -> SGPR loads) + 4x unroll for ILP.

__global__ void prop_kernel(const int* __restrict__ rowptr, const int* __restrict__ src,
                            const float* __restrict__ w, const float* __restrict__ h,
                            float* __restrict__ out, int N) {
    int gid = blockIdx.x * blockDim.x + threadIdx.x;
    int node = __builtin_amdgcn_readfirstlane(gid >> 6);  // wave-uniform
    int lane = threadIdx.x & 63;
    if (node >= N) return;
    int beg = rowptr[node], end = rowptr[node + 1];
    float acc = 0.0f;
    int j = beg;
    for (; j + 4 <= end; j += 4) {
        int s0 = src[j + 0], s1 = src[j + 1], s2 = src[j + 2], s3 = src[j + 3];
        float w0 = w[j + 0], w1 = w[j + 1], w2 = w[j + 2], w3 = w[j + 3];
        float h0 = h[(size_t)s0 * DIN + lane];
        float h1 = h[(size_t)s1 * DIN + lane];
        float h2 = h[(size_t)s2 * DIN + lane];
        float h3 = h[(size_t)s3 * DIN + lane];
        acc = fmaf(w0, h0, acc);
        acc = fmaf(w1, h1, acc);
        acc = fmaf(w2, h2, acc);
        acc = fmaf(w3, h3, acc);
    }
    for (; j < end; ++j) acc = fmaf(w[j], h[(size_t)src[j] * DIN + lane], acc);
    out[(size_t)node * DIN + lane] = acc;
}

// ---------------- dense matmul: out[N x DOUT] = H[N x 64] @ W[64 x DOUT] ----------------
// BM=64 rows/block, 256 threads, 4x4 register tile per thread.
// MODE 0: out = H@W   MODE 1: out = accin + H@W   MODE 2: out = relu(accin + H@W + bias)

template <int DOUT, int MODE>
__global__ __launch_bounds__(256) void mm_kernel(const float* __restrict__ H,
                                                 const float* __restrict__ W,
                                                 const float* __restrict__ bias,
                                                 const float* __restrict__ accin,
                                                 float* __restrict__ out, int N) {
    __shared__ float Ws[DIN][DOUT];
    __shared__ float Hs[64][DIN + 1];
    int tid = threadIdx.x;
    int row0 = blockIdx.x * 64;
    for (int i = tid; i < DIN * DOUT; i += 256) Ws[i / DOUT][i % DOUT] = W[i];
    // 64 rows x 64 cols, float4 per thread-iter
    for (int i = tid; i < 64 * 16; i += 256) {
        int r = i >> 4, k4 = (i & 15) * 4;
        int gr = row0 + r;
        float4 v = (gr < N) ? *(const float4*)&H[(size_t)gr * DIN + k4]
                            : make_float4(0.f, 0.f, 0.f, 0.f);
        Hs[r][k4 + 0] = v.x; Hs[r][k4 + 1] = v.y; Hs[r][k4 + 2] = v.z; Hs[r][k4 + 3] = v.w;
    }
    __syncthreads();
    constexpr int CT = DOUT / 4;  // col tiles (64->16, 40->10)
    int tile = tid;
    if (tile >= 16 * CT) return;
    int r0 = (tile / CT) * 4, c0 = (tile % CT) * 4;
    float a[4][4] = {};
#pragma unroll
    for (int k = 0; k < DIN; ++k) {
        float b0 = Ws[k][c0 + 0], b1 = Ws[k][c0 + 1], b2 = Ws[k][c0 + 2], b3 = Ws[k][c0 + 3];
        float h0 = Hs[r0 + 0][k], h1 = Hs[r0 + 1][k], h2 = Hs[r0 + 2][k], h3 = Hs[r0 + 3][k];
        a[0][0] = fmaf(h0, b0, a[0][0]); a[0][1] = fmaf(h0, b1, a[0][1]);
        a[0][2] = fmaf(h0, b2, a[0][2]); a[0][3] = fmaf(h0, b3, a[0][3]);
        a[1][0] = fmaf(h1, b0, a[1][0]); a[1][1] = fmaf(h1, b1, a[1][1]);
        a[1][2] = fmaf(h1, b2, a[1][2]); a[1][3] = fmaf(h1, b3, a[1][3]);
        a[2][0] = fmaf(h2, b0, a[2][0]); a[2][1] = fmaf(h2, b1, a[2][1]);
        a[2][2] = fmaf(h2, b2, a[2][2]); a[2][3] = fmaf(h2, b3, a[2][3]);
        a[3][0] = fmaf(h3, b0, a[3][0]); a[3][1] = fmaf(h3, b1, a[3][1]);
        a[3][2] = fmaf(h3, b2, a[3][2]); a[3][3] = fmaf(h3, b3, a[3][3]);
    }
#pragma unroll
    for (int i = 0; i < 4; ++i) {
        int gr = row0 + r0 + i;
        if (gr >= N) continue;
#pragma unroll
        for (int c = 0; c < 4; ++c) {
            size_t o = (size_t)gr * DOUT + c0 + c;
            if (MODE == 0) {
                out[o] = a[i][c];
            } else if (MODE == 1) {
                out[o] = accin[o] + a[i][c];
            } else {
                float v = accin[o] + a[i][c] + bias[c0 + c];
                out[o] = v > 0.0f ? v : 0.0f;
            }
        }
    }
}

// ---------------- log_softmax over rows of 40 (one wave per row) ----------------

__global__ void lsm_kernel(float* __restrict__ out, const float* __restrict__ bias, int N) {
    int gid = blockIdx.x * blockDim.x + threadIdx.x;
    int row = gid >> 6;
    int lane = gid & 63;
    if (row >= N) return;
    float v = (lane < 40) ? out[(size_t)row * 40 + lane] + bias[lane] : -INFINITY;
    float m = v;
    for (int off = 32; off > 0; off >>= 1) m = fmaxf(m, __shfl_xor(m, off, 64));
    float e = (lane < 40) ? expf(v - m) : 0.0f;
    float ssum = e;
    for (int off = 32; off > 0; off >>= 1) ssum += __shfl_xor(ssum, off, 64);
    if (lane < 40) out[(size_t)row * 40 + lane] = v - m - logf(ssum);
}

// ---------------- launch ----------------

extern "C" void kernel_launch(void* const* d_in, const int* in_sizes, int n_in,
                              void* d_out, int out_size, void* d_ws, size_t ws_size,
                              hipStream_t stream) {
    const float* x  = (const float*)d_in[0];
    const int*   ei = (const int*)d_in[1];
    const float* W1 = (const float*)d_in[2];
    const float* b1 = (const float*)d_in[3];
    const float* W2 = (const float*)d_in[4];
    const float* b2 = (const float*)d_in[5];

    int N = in_sizes[0] / DIN;
    int E = in_sizes[1] / 2;
    const int* rowv = ei;       // edge_index[0] = message source
    const int* colv = ei + E;   // edge_index[1] = destination (segment id)

    char* p = (char*)d_ws;
    auto alloc = [&](size_t bytes) {
        char* q = p;
        p += (bytes + 255) & ~(size_t)255;
        return q;
    };
    int*   cnt    = (int*)alloc((size_t)N * 4);
    int*   cursor = (int*)alloc((size_t)N * 4);
    int*   rowptr = (int*)alloc((size_t)(N + 1) * 4);
    float* dinv   = (float*)alloc((size_t)N * 4);
    int*   bsum   = (int*)alloc(1024 * 4);
    int*   boff   = (int*)alloc(1024 * 4);
    int*   src    = (int*)alloc((size_t)E * 4);
    float* w      = (float*)alloc((size_t)E * 4);
    float* t1     = (float*)alloc((size_t)N * DIN * 4);
    float* t2     = (float*)alloc((size_t)N * DIN * 4);
    float* acc    = (float*)alloc((size_t)N * DIN * 4);
    float* outp   = (float*)d_out;

    hipMemsetAsync(cnt, 0, (size_t)N * 4, stream);
    hipMemsetAsync(cursor, 0, (size_t)N * 4, stream);

    const int tpb = 256;
    int B = (N + 1023) / 1024;  // scan blocks (98 for N=100K, supports N<=1M)

    hist_kernel<<<1024, tpb, 0, stream>>>(colv, cnt, E);
    dinv_kernel<<<(N + tpb - 1) / tpb, tpb, 0, stream>>>(cnt, dinv, N);
    scanA_kernel<<<B, 256, 0, stream>>>(cnt, bsum, N);
    scanB_kernel<<<1, 1024, 0, stream>>>(bsum, boff, rowptr, B, N);
    scanC_kernel<<<B, 256, 0, stream>>>(cnt, boff, rowptr, N);
    fill_kernel<<<1024, tpb, 0, stream>>>(rowv, colv, rowptr, cursor, dinv, src, w, E);

    int propBlocks = (N * 64 + tpb - 1) / tpb;  // one wave per node
    int mmBlocks = (N + 63) / 64;

    // ---- layer 1: acc = x@W1[0] + sum_k prop^k(x)@W1[k]; h = relu(acc + b1) -> t2
    mm_kernel<64, 0><<<mmBlocks, 256, 0, stream>>>(x, W1 + 0 * 64 * 64, nullptr, nullptr, acc, N);
    prop_kernel<<<propBlocks, tpb, 0, stream>>>(rowptr, src, w, x, t1, N);
    mm_kernel<64, 1><<<mmBlocks, 256, 0, stream>>>(t1, W1 + 1 * 64 * 64, nullptr, acc, acc, N);
    prop_kernel<<<propBlocks, tpb, 0, stream>>>(rowptr, src, w, t1, t2, N);
    mm_kernel<64, 1><<<mmBlocks, 256, 0, stream>>>(t2, W1 + 2 * 64 * 64, nullptr, acc, acc, N);
    prop_kernel<<<propBlocks, tpb, 0, stream>>>(rowptr, src, w, t2, t1, N);
    mm_kernel<64, 2><<<mmBlocks, 256, 0, stream>>>(t1, W1 + 3 * 64 * 64, b1, acc, t2, N);

    // ---- layer 2: out = h@W2[0] + sum_k prop^k(h)@W2[k]  (h = t2), b2 folded into lsm
    mm_kernel<40, 0><<<mmBlocks, 256, 0, stream>>>(t2, W2 + 0 * 64 * 40, nullptr, nullptr, outp, N);
    prop_kernel<<<propBlocks, tpb, 0, stream>>>(rowptr, src, w, t2, t1, N);
    mm_kernel<40, 1><<<mmBlocks, 256, 0, stream>>>(t1, W2 + 1 * 64 * 40, nullptr, outp, outp, N);
    prop_kernel<<<propBlocks, tpb, 0, stream>>>(rowptr, src, w, t1, t2, N);
    mm_kernel<40, 1><<<mmBlocks, 256, 0, stream>>>(t2, W2 + 2 * 64 * 40, nullptr, outp, outp, N);
    prop_kernel<<<propBlocks, tpb, 0, stream>>>(rowptr, src, w, t2, t1, N);
    mm_kernel<40, 1><<<mmBlocks, 256, 0, stream>>>(t1, W2 + 3 * 64 * 40, nullptr, outp, outp, N);

    lsm_kernel<<<propBlocks, tpb, 0, stream>>>(outp, b2, N);
}

// Round 3
// 764.945 us; speedup vs baseline: 2.1292x; 1.2598x over previous
//
#include <hip/hip_runtime.h>
#include <math.h>

#define DIN 64

// ---------------- CSR construction ----------------

__global__ void hist_kernel(const int* __restrict__ col, int* __restrict__ cnt, int E) {
    int i = blockIdx.x * blockDim.x + threadIdx.x;
    int stride = gridDim.x * blockDim.x;
    for (; i < E; i += stride) atomicAdd(&cnt[col[i]], 1);
}

__global__ void dinv_kernel(const int* __restrict__ cnt, float* __restrict__ dinv, int N) {
    int i = blockIdx.x * blockDim.x + threadIdx.x;
    if (i < N) {
        int c = cnt[i];
        dinv[i] = (c > 0) ? rsqrtf((float)c) : 0.0f;
    }
}

// ---- 3-phase exclusive scan of cnt[N] -> rowptr[N+1] ----

__global__ void scanA_kernel(const int* __restrict__ cnt, int* __restrict__ bsum, int N) {
    __shared__ int sm[256];
    int tid = threadIdx.x;
    int base = blockIdx.x * 1024 + tid * 4;
    int s = 0;
#pragma unroll
    for (int i = 0; i < 4; ++i) {
        int idx = base + i;
        if (idx < N) s += cnt[idx];
    }
    sm[tid] = s;
    __syncthreads();
    for (int off = 128; off > 0; off >>= 1) {
        if (tid < off) sm[tid] += sm[tid + off];
        __syncthreads();
    }
    if (tid == 0) bsum[blockIdx.x] = sm[0];
}

__global__ void scanB_kernel(const int* __restrict__ bsum, int* __restrict__ boff,
                             int* __restrict__ rowptr, int B, int N) {
    __shared__ int sm[1024];
    int tid = threadIdx.x;
    int v = (tid < B) ? bsum[tid] : 0;
    sm[tid] = v;
    __syncthreads();
    for (int off = 1; off < 1024; off <<= 1) {
        int add = (tid >= off) ? sm[tid - off] : 0;
        __syncthreads();
        sm[tid] += add;
        __syncthreads();
    }
    if (tid < B) boff[tid] = sm[tid] - v;  // exclusive
    if (tid == 1023) rowptr[N] = sm[1023]; // total = E
}

__global__ void scanC_kernel(const int* __restrict__ cnt, const int* __restrict__ boff,
                             int* __restrict__ rowptr, int N) {
    __shared__ int sm[256];
    int tid = threadIdx.x;
    int base = blockIdx.x * 1024 + tid * 4;
    int v[4];
    int s = 0;
#pragma unroll
    for (int i = 0; i < 4; ++i) {
        int idx = base + i;
        v[i] = (idx < N) ? cnt[idx] : 0;
        s += v[i];
    }
    sm[tid] = s;
    __syncthreads();
    for (int off = 1; off < 256; off <<= 1) {
        int add = (tid >= off) ? sm[tid - off] : 0;
        __syncthreads();
        sm[tid] += add;
        __syncthreads();
    }
    int run = boff[blockIdx.x] + sm[tid] - s;
#pragma unroll
    for (int i = 0; i < 4; ++i) {
        int idx = base + i;
        if (idx < N) rowptr[idx] = run;
        run += v[i];
    }
}

// fill: single 8B (src, w-bits) store per edge — one dirty line instead of two.
__global__ void fill_kernel(const int* __restrict__ row, const int* __restrict__ col,
                            const int* __restrict__ rowptr, int* __restrict__ cursor,
                            const float* __restrict__ dinv,
                            int2* __restrict__ sw, int E) {
    int i = blockIdx.x * blockDim.x + threadIdx.x;
    int stride = gridDim.x * blockDim.x;
    for (; i < E; i += stride) {
        int c = col[i];
        int r = row[i];
        int p = rowptr[c] + atomicAdd(&cursor[c], 1);
        sw[p] = make_int2(r, __float_as_int(dinv[r] * dinv[c]));
    }
}

// ---------------- propagation ----------------
// One wave per node. 4 groups of 16 lanes; group g handles edges beg+g, beg+g+4, ...
// Each group loads the full 256B source row as float4/lane -> 4 edges in flight,
// 4x fewer VMEM instructions. Cross-group butterfly reduce at the end.

__global__ __launch_bounds__(256) void prop_kernel(const int* __restrict__ rowptr,
                                                   const int2* __restrict__ sw,
                                                   const float* __restrict__ h,
                                                   float* __restrict__ out, int N) {
    int gid = blockIdx.x * blockDim.x + threadIdx.x;
    int node = gid >> 6;
    if (node >= N) return;
    int lane = threadIdx.x & 63;
    int g = lane >> 4, l = lane & 15;
    int beg = rowptr[node], end = rowptr[node + 1];
    float4 acc = make_float4(0.f, 0.f, 0.f, 0.f);
    for (int j = beg + g; j < end; j += 4) {
        int2 e = sw[j];
        float ww = __int_as_float(e.y);
        float4 hv = *(const float4*)&h[(size_t)e.x * DIN + l * 4];
        acc.x = fmaf(ww, hv.x, acc.x);
        acc.y = fmaf(ww, hv.y, acc.y);
        acc.z = fmaf(ww, hv.z, acc.z);
        acc.w = fmaf(ww, hv.w, acc.w);
    }
    // sum across the 4 groups (lanes l, l+16, l+32, l+48)
    acc.x += __shfl_xor(acc.x, 16, 64); acc.y += __shfl_xor(acc.y, 16, 64);
    acc.z += __shfl_xor(acc.z, 16, 64); acc.w += __shfl_xor(acc.w, 16, 64);
    acc.x += __shfl_xor(acc.x, 32, 64); acc.y += __shfl_xor(acc.y, 32, 64);
    acc.z += __shfl_xor(acc.z, 32, 64); acc.w += __shfl_xor(acc.w, 32, 64);
    if (g == 0) *(float4*)&out[(size_t)node * DIN + l * 4] = acc;
}

// ---------------- dense matmuls ----------------
// mm3: out[N x DOUT] = h0@W[0] + h1@W[1] + h2@W[2]   (W = [3+][64][DOUT] contiguous)
// 64 rows/block, 256 threads, 4x4 register tile, K processed in 3 chunks of 64.

template <int DOUT>
__global__ __launch_bounds__(256) void mm3_kernel(const float* __restrict__ h0,
                                                  const float* __restrict__ h1,
                                                  const float* __restrict__ h2,
                                                  const float* __restrict__ W,
                                                  float* __restrict__ out, int N) {
    __shared__ float Ws[DIN][DOUT];
    __shared__ float Hs[64][DIN + 1];
    const float* hp[3] = {h0, h1, h2};
    int tid = threadIdx.x;
    int row0 = blockIdx.x * 64;
    constexpr int CT = DOUT / 4;
    int r0 = (tid / CT) * 4, c0 = (tid % CT) * 4;
    float a[4][4] = {};
#pragma unroll
    for (int kk = 0; kk < 3; ++kk) {
        for (int i = tid; i < DIN * DOUT; i += 256) Ws[i / DOUT][i % DOUT] = W[kk * DIN * DOUT + i];
        for (int i = tid; i < 64 * 16; i += 256) {
            int r = i >> 4, k4 = (i & 15) * 4;
            int gr = row0 + r;
            float4 v = (gr < N) ? *(const float4*)&hp[kk][(size_t)gr * DIN + k4]
                                : make_float4(0.f, 0.f, 0.f, 0.f);
            Hs[r][k4 + 0] = v.x; Hs[r][k4 + 1] = v.y; Hs[r][k4 + 2] = v.z; Hs[r][k4 + 3] = v.w;
        }
        __syncthreads();
        if (tid < 16 * CT) {
#pragma unroll
            for (int k = 0; k < DIN; ++k) {
                float b0 = Ws[k][c0 + 0], b1 = Ws[k][c0 + 1], b2 = Ws[k][c0 + 2], b3 = Ws[k][c0 + 3];
                float q0 = Hs[r0 + 0][k], q1 = Hs[r0 + 1][k], q2 = Hs[r0 + 2][k], q3 = Hs[r0 + 3][k];
                a[0][0] = fmaf(q0, b0, a[0][0]); a[0][1] = fmaf(q0, b1, a[0][1]);
                a[0][2] = fmaf(q0, b2, a[0][2]); a[0][3] = fmaf(q0, b3, a[0][3]);
                a[1][0] = fmaf(q1, b0, a[1][0]); a[1][1] = fmaf(q1, b1, a[1][1]);
                a[1][2] = fmaf(q1, b2, a[1][2]); a[1][3] = fmaf(q1, b3, a[1][3]);
                a[2][0] = fmaf(q2, b0, a[2][0]); a[2][1] = fmaf(q2, b1, a[2][1]);
                a[2][2] = fmaf(q2, b2, a[2][2]); a[2][3] = fmaf(q2, b3, a[2][3]);
                a[3][0] = fmaf(q3, b0, a[3][0]); a[3][1] = fmaf(q3, b1, a[3][1]);
                a[3][2] = fmaf(q3, b2, a[3][2]); a[3][3] = fmaf(q3, b3, a[3][3]);
            }
        }
        __syncthreads();
    }
    if (tid >= 16 * CT) return;
#pragma unroll
    for (int i = 0; i < 4; ++i) {
        int gr = row0 + r0 + i;
        if (gr >= N) continue;
#pragma unroll
        for (int c = 0; c < 4; ++c) out[(size_t)gr * DOUT + c0 + c] = a[i][c];
    }
}

// mm: single-W matmul with accumulate / relu epilogue.
// MODE 1: out = accin + H@W   MODE 2: out = relu(accin + H@W + bias)

template <int DOUT, int MODE>
__global__ __launch_bounds__(256) void mm_kernel(const float* __restrict__ H,
                                                 const float* __restrict__ W,
                                                 const float* __restrict__ bias,
                                                 const float* __restrict__ accin,
                                                 float* __restrict__ out, int N) {
    __shared__ float Ws[DIN][DOUT];
    __shared__ float Hs[64][DIN + 1];
    int tid = threadIdx.x;
    int row0 = blockIdx.x * 64;
    for (int i = tid; i < DIN * DOUT; i += 256) Ws[i / DOUT][i % DOUT] = W[i];
    for (int i = tid; i < 64 * 16; i += 256) {
        int r = i >> 4, k4 = (i & 15) * 4;
        int gr = row0 + r;
        float4 v = (gr < N) ? *(const float4*)&H[(size_t)gr * DIN + k4]
                            : make_float4(0.f, 0.f, 0.f, 0.f);
        Hs[r][k4 + 0] = v.x; Hs[r][k4 + 1] = v.y; Hs[r][k4 + 2] = v.z; Hs[r][k4 + 3] = v.w;
    }
    __syncthreads();
    constexpr int CT = DOUT / 4;
    if (tid >= 16 * CT) return;
    int r0 = (tid / CT) * 4, c0 = (tid % CT) * 4;
    float a[4][4] = {};
#pragma unroll
    for (int k = 0; k < DIN; ++k) {
        float b0 = Ws[k][c0 + 0], b1 = Ws[k][c0 + 1], b2 = Ws[k][c0 + 2], b3 = Ws[k][c0 + 3];
        float q0 = Hs[r0 + 0][k], q1 = Hs[r0 + 1][k], q2 = Hs[r0 + 2][k], q3 = Hs[r0 + 3][k];
        a[0][0] = fmaf(q0, b0, a[0][0]); a[0][1] = fmaf(q0, b1, a[0][1]);
        a[0][2] = fmaf(q0, b2, a[0][2]); a[0][3] = fmaf(q0, b3, a[0][3]);
        a[1][0] = fmaf(q1, b0, a[1][0]); a[1][1] = fmaf(q1, b1, a[1][1]);
        a[1][2] = fmaf(q1, b2, a[1][2]); a[1][3] = fmaf(q1, b3, a[1][3]);
        a[2][0] = fmaf(q2, b0, a[2][0]); a[2][1] = fmaf(q2, b1, a[2][1]);
        a[2][2] = fmaf(q2, b2, a[2][2]); a[2][3] = fmaf(q2, b3, a[2][3]);
        a[3][0] = fmaf(q3, b0, a[3][0]); a[3][1] = fmaf(q3, b1, a[3][1]);
        a[3][2] = fmaf(q3, b2, a[3][2]); a[3][3] = fmaf(q3, b3, a[3][3]);
    }
#pragma unroll
    for (int i = 0; i < 4; ++i) {
        int gr = row0 + r0 + i;
        if (gr >= N) continue;
#pragma unroll
        for (int c = 0; c < 4; ++c) {
            size_t o = (size_t)gr * DOUT + c0 + c;
            if (MODE == 1) {
                out[o] = accin[o] + a[i][c];
            } else {
                float v = accin[o] + a[i][c] + bias[c0 + c];
                out[o] = v > 0.0f ? v : 0.0f;
            }
        }
    }
}

// ---------------- log_softmax over rows of 40 (one wave per row) ----------------

__global__ void lsm_kernel(float* __restrict__ out, const float* __restrict__ bias, int N) {
    int gid = blockIdx.x * blockDim.x + threadIdx.x;
    int row = gid >> 6;
    int lane = gid & 63;
    if (row >= N) return;
    float v = (lane < 40) ? out[(size_t)row * 40 + lane] + bias[lane] : -INFINITY;
    float m = v;
    for (int off = 32; off > 0; off >>= 1) m = fmaxf(m, __shfl_xor(m, off, 64));
    float e = (lane < 40) ? expf(v - m) : 0.0f;
    float ssum = e;
    for (int off = 32; off > 0; off >>= 1) ssum += __shfl_xor(ssum, off, 64);
    if (lane < 40) out[(size_t)row * 40 + lane] = v - m - logf(ssum);
}

// ---------------- launch ----------------

extern "C" void kernel_launch(void* const* d_in, const int* in_sizes, int n_in,
                              void* d_out, int out_size, void* d_ws, size_t ws_size,
                              hipStream_t stream) {
    const float* x  = (const float*)d_in[0];
    const int*   ei = (const int*)d_in[1];
    const float* W1 = (const float*)d_in[2];
    const float* b1 = (const float*)d_in[3];
    const float* W2 = (const float*)d_in[4];
    const float* b2 = (const float*)d_in[5];

    int N = in_sizes[0] / DIN;
    int E = in_sizes[1] / 2;
    const int* rowv = ei;       // edge_index[0] = message source
    const int* colv = ei + E;   // edge_index[1] = destination (segment id)

    char* p = (char*)d_ws;
    auto alloc = [&](size_t bytes) {
        char* q = p;
        p += (bytes + 255) & ~(size_t)255;
        return q;
    };
    int*   cnt    = (int*)alloc((size_t)N * 4);
    int*   cursor = (int*)alloc((size_t)N * 4);
    int*   rowptr = (int*)alloc((size_t)(N + 1) * 4);
    float* dinv   = (float*)alloc((size_t)N * 4);
    int*   bsum   = (int*)alloc(1024 * 4);
    int*   boff   = (int*)alloc(1024 * 4);
    int2*  sw     = (int2*)alloc((size_t)E * 8);
    float* t1     = (float*)alloc((size_t)N * DIN * 4);
    float* t2     = (float*)alloc((size_t)N * DIN * 4);
    float* acc    = (float*)alloc((size_t)N * DIN * 4);
    float* outp   = (float*)d_out;

    hipMemsetAsync(cnt, 0, (size_t)N * 4, stream);
    hipMemsetAsync(cursor, 0, (size_t)N * 4, stream);

    const int tpb = 256;
    int B = (N + 1023) / 1024;

    hist_kernel<<<1024, tpb, 0, stream>>>(colv, cnt, E);
    dinv_kernel<<<(N + tpb - 1) / tpb, tpb, 0, stream>>>(cnt, dinv, N);
    scanA_kernel<<<B, 256, 0, stream>>>(cnt, bsum, N);
    scanB_kernel<<<1, 1024, 0, stream>>>(bsum, boff, rowptr, B, N);
    scanC_kernel<<<B, 256, 0, stream>>>(cnt, boff, rowptr, N);
    fill_kernel<<<1024, tpb, 0, stream>>>(rowv, colv, rowptr, cursor, dinv, sw, E);

    int propBlocks = (N * 64 + tpb - 1) / tpb;  // one wave per node
    int mmBlocks = (N + 63) / 64;

    // ---- layer 1: acc = x@W1[0] + h1@W1[1] + h2@W1[2]; h = relu(acc + h3@W1[3] + b1)
    prop_kernel<<<propBlocks, tpb, 0, stream>>>(rowptr, sw, x, t1, N);   // h1 -> t1
    prop_kernel<<<propBlocks, tpb, 0, stream>>>(rowptr, sw, t1, t2, N);  // h2 -> t2
    mm3_kernel<64><<<mmBlocks, 256, 0, stream>>>(x, t1, t2, W1, acc, N);
    prop_kernel<<<propBlocks, tpb, 0, stream>>>(rowptr, sw, t2, t1, N);  // h3 -> t1
    mm_kernel<64, 2><<<mmBlocks, 256, 0, stream>>>(t1, W1 + 3 * 64 * 64, b1, acc, t2, N);  // h -> t2

    // ---- layer 2: out = h@W2[0] + q1@W2[1] + q2@W2[2] + q3@W2[3]; b2 folded into lsm
    prop_kernel<<<propBlocks, tpb, 0, stream>>>(rowptr, sw, t2, t1, N);   // q1 -> t1
    prop_kernel<<<propBlocks, tpb, 0, stream>>>(rowptr, sw, t1, acc, N);  // q2 -> acc
    mm3_kernel<40><<<mmBlocks, 256, 0, stream>>>(t2, t1, acc, W2, outp, N);
    prop_kernel<<<propBlocks, tpb, 0, stream>>>(rowptr, sw, acc, t1, N);  // q3 -> t1
    mm_kernel<40, 1><<<mmBlocks, 256, 0, stream>>>(t1, W2 + 3 * 64 * 40, nullptr, outp, outp, N);

    lsm_kernel<<<propBlocks, tpb, 0, stream>>>(outp, b2, N);
}

// Round 4
// 730.077 us; speedup vs baseline: 2.2308x; 1.0478x over previous
//
#include <hip/hip_runtime.h>
#include <math.h>

#define DIN 64

// ---------------- bf16 helpers (RNE) ----------------

__device__ __forceinline__ float bf2f(unsigned short u) {
    return __uint_as_float(((unsigned int)u) << 16);
}
__device__ __forceinline__ unsigned short f2bf(float f) {
    unsigned int u = __float_as_uint(f);
    return (unsigned short)((u + 0x7fffu + ((u >> 16) & 1u)) >> 16);
}

// ---------------- CSR construction (XCD-partitioned) ----------------
// Blocks with blockIdx%8==x handle node range [N*x/8, N*(x+1)/8): all atomics/
// writes to a given cnt/sw region come from one XCD -> lines stay L2-resident
// and fill completely before writeback. Correct regardless of actual mapping.

__global__ void histp_kernel(const int* __restrict__ col, int* __restrict__ cnt,
                             int E, int N) {
    int xcd = blockIdx.x & 7, gb = blockIdx.x >> 3;
    int lo = (int)((long long)N * xcd / 8), hi = (int)((long long)N * (xcd + 1) / 8);
    int stride = (gridDim.x >> 3) * blockDim.x;
    for (int i = gb * blockDim.x + threadIdx.x; i < E; i += stride) {
        int c = col[i];
        if (c >= lo && c < hi) atomicAdd(&cnt[c], 1);
    }
}

__global__ void dinv_kernel(const int* __restrict__ cnt, float* __restrict__ dinv, int N) {
    int i = blockIdx.x * blockDim.x + threadIdx.x;
    if (i < N) {
        int c = cnt[i];
        dinv[i] = (c > 0) ? rsqrtf((float)c) : 0.0f;
    }
}

// ---- 3-phase exclusive scan of cnt[N] -> rowptr[N+1] ----

__global__ void scanA_kernel(const int* __restrict__ cnt, int* __restrict__ bsum, int N) {
    __shared__ int sm[256];
    int tid = threadIdx.x;
    int base = blockIdx.x * 1024 + tid * 4;
    int s = 0;
#pragma unroll
    for (int i = 0; i < 4; ++i) {
        int idx = base + i;
        if (idx < N) s += cnt[idx];
    }
    sm[tid] = s;
    __syncthreads();
    for (int off = 128; off > 0; off >>= 1) {
        if (tid < off) sm[tid] += sm[tid + off];
        __syncthreads();
    }
    if (tid == 0) bsum[blockIdx.x] = sm[0];
}

__global__ void scanB_kernel(const int* __restrict__ bsum, int* __restrict__ boff,
                             int* __restrict__ rowptr, int B, int N) {
    __shared__ int sm[1024];
    int tid = threadIdx.x;
    int v = (tid < B) ? bsum[tid] : 0;
    sm[tid] = v;
    __syncthreads();
    for (int off = 1; off < 1024; off <<= 1) {
        int add = (tid >= off) ? sm[tid - off] : 0;
        __syncthreads();
        sm[tid] += add;
        __syncthreads();
    }
    if (tid < B) boff[tid] = sm[tid] - v;  // exclusive
    if (tid == 1023) rowptr[N] = sm[1023]; // total = E
}

__global__ void scanC_kernel(const int* __restrict__ cnt, const int* __restrict__ boff,
                             int* __restrict__ rowptr, int N) {
    __shared__ int sm[256];
    int tid = threadIdx.x;
    int base = blockIdx.x * 1024 + tid * 4;
    int v[4];
    int s = 0;
#pragma unroll
    for (int i = 0; i < 4; ++i) {
        int idx = base + i;
        v[i] = (idx < N) ? cnt[idx] : 0;
        s += v[i];
    }
    sm[tid] = s;
    __syncthreads();
    for (int off = 1; off < 256; off <<= 1) {
        int add = (tid >= off) ? sm[tid - off] : 0;
        __syncthreads();
        sm[tid] += add;
        __syncthreads();
    }
    int run = boff[blockIdx.x] + sm[tid] - s;
#pragma unroll
    for (int i = 0; i < 4; ++i) {
        int idx = base + i;
        if (idx < N) rowptr[idx] = run;
        run += v[i];
    }
}

__global__ void fillp_kernel(const int* __restrict__ row, const int* __restrict__ col,
                             const int* __restrict__ rowptr, int* __restrict__ cursor,
                             const float* __restrict__ dinv,
                             int2* __restrict__ sw, int E, int N) {
    int xcd = blockIdx.x & 7, gb = blockIdx.x >> 3;
    int lo = (int)((long long)N * xcd / 8), hi = (int)((long long)N * (xcd + 1) / 8);
    int stride = (gridDim.x >> 3) * blockDim.x;
    for (int i = gb * blockDim.x + threadIdx.x; i < E; i += stride) {
        int c = col[i];
        if (c >= lo && c < hi) {
            int r = row[i];
            int p = rowptr[c] + atomicAdd(&cursor[c], 1);
            sw[p] = make_int2(r, __float_as_int(dinv[r] * dinv[c]));
        }
    }
}

// ---------------- f32 -> bf16 row conversion ----------------

__global__ void cvt_kernel(const float* __restrict__ x, unsigned short* __restrict__ xb,
                           int n4) {  // n4 = total elems / 4
    int i = blockIdx.x * blockDim.x + threadIdx.x;
    if (i >= n4) return;
    float4 v = *(const float4*)&x[(size_t)i * 4];
    ushort4 o;
    o.x = f2bf(v.x); o.y = f2bf(v.y); o.z = f2bf(v.z); o.w = f2bf(v.w);
    *(ushort4*)&xb[(size_t)i * 4] = o;
}

// ---------------- propagation ----------------
// One wave per node; 4 groups of 16 lanes; group g handles edges beg+g, beg+g+4,...
// Source rows gathered as bf16 (128B/row), f32 accumulate. Writes f32 out
// (for matmuls) and optionally a bf16 copy (for the next prop).

template <bool WB>
__global__ __launch_bounds__(256) void prop_kernel(const int* __restrict__ rowptr,
                                                   const int2* __restrict__ sw,
                                                   const unsigned short* __restrict__ hb,
                                                   float* __restrict__ out,
                                                   unsigned short* __restrict__ outb, int N) {
    int gid = blockIdx.x * blockDim.x + threadIdx.x;
    int node = gid >> 6;
    if (node >= N) return;
    int lane = threadIdx.x & 63;
    int g = lane >> 4, l = lane & 15;
    int beg = rowptr[node], end = rowptr[node + 1];
    float a0 = 0.f, a1 = 0.f, a2 = 0.f, a3 = 0.f;
    for (int j = beg + g; j < end; j += 4) {
        int2 e = sw[j];
        float ww = __int_as_float(e.y);
        ushort4 hv = *(const ushort4*)&hb[(size_t)e.x * DIN + l * 4];
        a0 = fmaf(ww, bf2f(hv.x), a0);
        a1 = fmaf(ww, bf2f(hv.y), a1);
        a2 = fmaf(ww, bf2f(hv.z), a2);
        a3 = fmaf(ww, bf2f(hv.w), a3);
    }
    a0 += __shfl_xor(a0, 16, 64); a1 += __shfl_xor(a1, 16, 64);
    a2 += __shfl_xor(a2, 16, 64); a3 += __shfl_xor(a3, 16, 64);
    a0 += __shfl_xor(a0, 32, 64); a1 += __shfl_xor(a1, 32, 64);
    a2 += __shfl_xor(a2, 32, 64); a3 += __shfl_xor(a3, 32, 64);
    if (g == 0) {
        *(float4*)&out[(size_t)node * DIN + l * 4] = make_float4(a0, a1, a2, a3);
        if (WB) {
            ushort4 o;
            o.x = f2bf(a0); o.y = f2bf(a1); o.z = f2bf(a2); o.w = f2bf(a3);
            *(ushort4*)&outb[(size_t)node * DIN + l * 4] = o;
        }
    }
}

// ---------------- dense matmuls ----------------
// mm3: out[N x DOUT] = h0@W[0] + h1@W[1] + h2@W[2]

template <int DOUT>
__global__ __launch_bounds__(256) void mm3_kernel(const float* __restrict__ h0,
                                                  const float* __restrict__ h1,
                                                  const float* __restrict__ h2,
                                                  const float* __restrict__ W,
                                                  float* __restrict__ out, int N) {
    __shared__ float Ws[DIN][DOUT];
    __shared__ float Hs[64][DIN + 1];
    const float* hp[3] = {h0, h1, h2};
    int tid = threadIdx.x;
    int row0 = blockIdx.x * 64;
    constexpr int CT = DOUT / 4;
    int r0 = (tid / CT) * 4, c0 = (tid % CT) * 4;
    float a[4][4] = {};
#pragma unroll
    for (int kk = 0; kk < 3; ++kk) {
        for (int i = tid; i < DIN * DOUT; i += 256) Ws[i / DOUT][i % DOUT] = W[kk * DIN * DOUT + i];
        for (int i = tid; i < 64 * 16; i += 256) {
            int r = i >> 4, k4 = (i & 15) * 4;
            int gr = row0 + r;
            float4 v = (gr < N) ? *(const float4*)&hp[kk][(size_t)gr * DIN + k4]
                                : make_float4(0.f, 0.f, 0.f, 0.f);
            Hs[r][k4 + 0] = v.x; Hs[r][k4 + 1] = v.y; Hs[r][k4 + 2] = v.z; Hs[r][k4 + 3] = v.w;
        }
        __syncthreads();
        if (tid < 16 * CT) {
#pragma unroll
            for (int k = 0; k < DIN; ++k) {
                float b0 = Ws[k][c0 + 0], b1 = Ws[k][c0 + 1], b2 = Ws[k][c0 + 2], b3 = Ws[k][c0 + 3];
                float q0 = Hs[r0 + 0][k], q1 = Hs[r0 + 1][k], q2 = Hs[r0 + 2][k], q3 = Hs[r0 + 3][k];
                a[0][0] = fmaf(q0, b0, a[0][0]); a[0][1] = fmaf(q0, b1, a[0][1]);
                a[0][2] = fmaf(q0, b2, a[0][2]); a[0][3] = fmaf(q0, b3, a[0][3]);
                a[1][0] = fmaf(q1, b0, a[1][0]); a[1][1] = fmaf(q1, b1, a[1][1]);
                a[1][2] = fmaf(q1, b2, a[1][2]); a[1][3] = fmaf(q1, b3, a[1][3]);
                a[2][0] = fmaf(q2, b0, a[2][0]); a[2][1] = fmaf(q2, b1, a[2][1]);
                a[2][2] = fmaf(q2, b2, a[2][2]); a[2][3] = fmaf(q2, b3, a[2][3]);
                a[3][0] = fmaf(q3, b0, a[3][0]); a[3][1] = fmaf(q3, b1, a[3][1]);
                a[3][2] = fmaf(q3, b2, a[3][2]); a[3][3] = fmaf(q3, b3, a[3][3]);
            }
        }
        __syncthreads();
    }
    if (tid >= 16 * CT) return;
#pragma unroll
    for (int i = 0; i < 4; ++i) {
        int gr = row0 + r0 + i;
        if (gr >= N) continue;
#pragma unroll
        for (int c = 0; c < 4; ++c) out[(size_t)gr * DOUT + c0 + c] = a[i][c];
    }
}

// mm: single-W matmul with epilogue.
// MODE 1: out = accin + H@W     MODE 2: out = relu(accin + H@W + bias), + bf16 copy

template <int DOUT, int MODE>
__global__ __launch_bounds__(256) void mm_kernel(const float* __restrict__ H,
                                                 const float* __restrict__ W,
                                                 const float* __restrict__ bias,
                                                 const float* __restrict__ accin,
                                                 float* __restrict__ out,
                                                 unsigned short* __restrict__ outb, int N) {
    __shared__ float Ws[DIN][DOUT];
    __shared__ float Hs[64][DIN + 1];
    int tid = threadIdx.x;
    int row0 = blockIdx.x * 64;
    for (int i = tid; i < DIN * DOUT; i += 256) Ws[i / DOUT][i % DOUT] = W[i];
    for (int i = tid; i < 64 * 16; i += 256) {
        int r = i >> 4, k4 = (i & 15) * 4;
        int gr = row0 + r;
        float4 v = (gr < N) ? *(const float4*)&H[(size_t)gr * DIN + k4]
                            : make_float4(0.f, 0.f, 0.f, 0.f);
        Hs[r][k4 + 0] = v.x; Hs[r][k4 + 1] = v.y; Hs[r][k4 + 2] = v.z; Hs[r][k4 + 3] = v.w;
    }
    __syncthreads();
    constexpr int CT = DOUT / 4;
    if (tid >= 16 * CT) return;
    int r0 = (tid / CT) * 4, c0 = (tid % CT) * 4;
    float a[4][4] = {};
#pragma unroll
    for (int k = 0; k < DIN; ++k) {
        float b0 = Ws[k][c0 + 0], b1 = Ws[k][c0 + 1], b2 = Ws[k][c0 + 2], b3 = Ws[k][c0 + 3];
        float q0 = Hs[r0 + 0][k], q1 = Hs[r0 + 1][k], q2 = Hs[r0 + 2][k], q3 = Hs[r0 + 3][k];
        a[0][0] = fmaf(q0, b0, a[0][0]); a[0][1] = fmaf(q0, b1, a[0][1]);
        a[0][2] = fmaf(q0, b2, a[0][2]); a[0][3] = fmaf(q0, b3, a[0][3]);
        a[1][0] = fmaf(q1, b0, a[1][0]); a[1][1] = fmaf(q1, b1, a[1][1]);
        a[1][2] = fmaf(q1, b2, a[1][2]); a[1][3] = fmaf(q1, b3, a[1][3]);
        a[2][0] = fmaf(q2, b0, a[2][0]); a[2][1] = fmaf(q2, b1, a[2][1]);
        a[2][2] = fmaf(q2, b2, a[2][2]); a[2][3] = fmaf(q2, b3, a[2][3]);
        a[3][0] = fmaf(q3, b0, a[3][0]); a[3][1] = fmaf(q3, b1, a[3][1]);
        a[3][2] = fmaf(q3, b2, a[3][2]); a[3][3] = fmaf(q3, b3, a[3][3]);
    }
#pragma unroll
    for (int i = 0; i < 4; ++i) {
        int gr = row0 + r0 + i;
        if (gr >= N) continue;
        float v[4];
#pragma unroll
        for (int c = 0; c < 4; ++c) {
            size_t o = (size_t)gr * DOUT + c0 + c;
            if (MODE == 1) {
                out[o] = accin[o] + a[i][c];
            } else {
                v[c] = accin[o] + a[i][c] + bias[c0 + c];
                v[c] = v[c] > 0.0f ? v[c] : 0.0f;
                out[o] = v[c];
            }
        }
        if (MODE == 2) {
            ushort4 ob;
            ob.x = f2bf(v[0]); ob.y = f2bf(v[1]); ob.z = f2bf(v[2]); ob.w = f2bf(v[3]);
            *(ushort4*)&outb[(size_t)gr * DOUT + c0] = ob;
        }
    }
}

// ---------------- log_softmax over rows of 40 (one wave per row) ----------------

__global__ void lsm_kernel(float* __restrict__ out, const float* __restrict__ bias, int N) {
    int gid = blockIdx.x * blockDim.x + threadIdx.x;
    int row = gid >> 6;
    int lane = gid & 63;
    if (row >= N) return;
    float v = (lane < 40) ? out[(size_t)row * 40 + lane] + bias[lane] : -INFINITY;
    float m = v;
    for (int off = 32; off > 0; off >>= 1) m = fmaxf(m, __shfl_xor(m, off, 64));
    float e = (lane < 40) ? expf(v - m) : 0.0f;
    float ssum = e;
    for (int off = 32; off > 0; off >>= 1) ssum += __shfl_xor(ssum, off, 64);
    if (lane < 40) out[(size_t)row * 40 + lane] = v - m - logf(ssum);
}

// ---------------- launch ----------------

extern "C" void kernel_launch(void* const* d_in, const int* in_sizes, int n_in,
                              void* d_out, int out_size, void* d_ws, size_t ws_size,
                              hipStream_t stream) {
    const float* x  = (const float*)d_in[0];
    const int*   ei = (const int*)d_in[1];
    const float* W1 = (const float*)d_in[2];
    const float* b1 = (const float*)d_in[3];
    const float* W2 = (const float*)d_in[4];
    const float* b2 = (const float*)d_in[5];

    int N = in_sizes[0] / DIN;
    int E = in_sizes[1] / 2;
    const int* rowv = ei;       // edge_index[0] = message source
    const int* colv = ei + E;   // edge_index[1] = destination (segment id)

    char* p = (char*)d_ws;
    auto alloc = [&](size_t bytes) {
        char* q = p;
        p += (bytes + 255) & ~(size_t)255;
        return q;
    };
    int*   cnt    = (int*)alloc((size_t)N * 4);
    int*   cursor = (int*)alloc((size_t)N * 4);
    int*   rowptr = (int*)alloc((size_t)(N + 1) * 4);
    float* dinv   = (float*)alloc((size_t)N * 4);
    int*   bsum   = (int*)alloc(1024 * 4);
    int*   boff   = (int*)alloc(1024 * 4);
    int2*  sw     = (int2*)alloc((size_t)E * 8);
    float* t1     = (float*)alloc((size_t)N * DIN * 4);
    float* t2     = (float*)alloc((size_t)N * DIN * 4);
    float* acc    = (float*)alloc((size_t)N * DIN * 4);
    unsigned short* bfA = (unsigned short*)alloc((size_t)N * DIN * 2);
    unsigned short* bfB = (unsigned short*)alloc((size_t)N * DIN * 2);
    float* outp   = (float*)d_out;

    hipMemsetAsync(cnt, 0, (size_t)N * 4, stream);
    hipMemsetAsync(cursor, 0, (size_t)N * 4, stream);

    const int tpb = 256;
    int B = (N + 1023) / 1024;

    histp_kernel<<<1024, tpb, 0, stream>>>(colv, cnt, E, N);
    dinv_kernel<<<(N + tpb - 1) / tpb, tpb, 0, stream>>>(cnt, dinv, N);
    scanA_kernel<<<B, 256, 0, stream>>>(cnt, bsum, N);
    scanB_kernel<<<1, 1024, 0, stream>>>(bsum, boff, rowptr, B, N);
    scanC_kernel<<<B, 256, 0, stream>>>(cnt, boff, rowptr, N);
    fillp_kernel<<<1024, tpb, 0, stream>>>(rowv, colv, rowptr, cursor, dinv, sw, E, N);

    int propBlocks = (N * 64 + tpb - 1) / tpb;  // one wave per node
    int mmBlocks = (N + 63) / 64;
    int n4 = N * DIN / 4;
    cvt_kernel<<<(n4 + tpb - 1) / tpb, tpb, 0, stream>>>(x, bfA, n4);  // xb -> bfA

    // ---- layer 1
    prop_kernel<true><<<propBlocks, tpb, 0, stream>>>(rowptr, sw, bfA, t1, bfB, N);  // h1
    prop_kernel<true><<<propBlocks, tpb, 0, stream>>>(rowptr, sw, bfB, t2, bfA, N);  // h2
    mm3_kernel<64><<<mmBlocks, 256, 0, stream>>>(x, t1, t2, W1, acc, N);
    prop_kernel<false><<<propBlocks, tpb, 0, stream>>>(rowptr, sw, bfA, t1, nullptr, N);  // h3
    mm_kernel<64, 2><<<mmBlocks, 256, 0, stream>>>(t1, W1 + 3 * 64 * 64, b1, acc, t2, bfB, N);  // h

    // ---- layer 2 (b2 folded into lsm)
    prop_kernel<true><<<propBlocks, tpb, 0, stream>>>(rowptr, sw, bfB, t1, bfA, N);   // q1
    prop_kernel<true><<<propBlocks, tpb, 0, stream>>>(rowptr, sw, bfA, acc, bfB, N);  // q2
    mm3_kernel<40><<<mmBlocks, 256, 0, stream>>>(t2, t1, acc, W2, outp, N);
    prop_kernel<false><<<propBlocks, tpb, 0, stream>>>(rowptr, sw, bfB, t1, nullptr, N);  // q3
    mm_kernel<40, 1><<<mmBlocks, 256, 0, stream>>>(t1, W2 + 3 * 64 * 40, nullptr, outp, outp, nullptr, N);

    lsm_kernel<<<propBlocks, tpb, 0, stream>>>(outp, b2, N);
}

// Round 9
// 600.036 us; speedup vs baseline: 2.7143x; 1.2167x over previous
//
#include <hip/hip_runtime.h>
#include <math.h>

#define DIN 64

typedef unsigned short us8 __attribute__((ext_vector_type(8)));

// ---------------- bf16 helpers (RNE) ----------------

__device__ __forceinline__ float bf2f(unsigned short u) {
    return __uint_as_float(((unsigned int)u) << 16);
}
__device__ __forceinline__ unsigned short f2bf(float f) {
    unsigned int u = __float_as_uint(f);
    return (unsigned short)((u + 0x7fffu + ((u >> 16) & 1u)) >> 16);
}

// ---------------- degree histogram ----------------

__global__ void hist_kernel(const int* __restrict__ col, int* __restrict__ cnt, int E) {
    int i = blockIdx.x * blockDim.x + threadIdx.x;
    int stride = gridDim.x * blockDim.x;
    for (; i < E; i += stride) atomicAdd(&cnt[col[i]], 1);
}

__global__ void dinv_kernel(const int* __restrict__ cnt, float* __restrict__ dinv, int N) {
    int i = blockIdx.x * blockDim.x + threadIdx.x;
    if (i < N) {
        int c = cnt[i];
        dinv[i] = (c > 0) ? rsqrtf((float)c) : 0.0f;
    }
}

// ---- 3-phase exclusive scan of cnt[N] -> rowptr[N+1] ----

__global__ void scanA_kernel(const int* __restrict__ cnt, int* __restrict__ bsum, int N) {
    __shared__ int sm[256];
    int tid = threadIdx.x;
    int base = blockIdx.x * 1024 + tid * 4;
    int s = 0;
#pragma unroll
    for (int i = 0; i < 4; ++i) {
        int idx = base + i;
        if (idx < N) s += cnt[idx];
    }
    sm[tid] = s;
    __syncthreads();
    for (int off = 128; off > 0; off >>= 1) {
        if (tid < off) sm[tid] += sm[tid + off];
        __syncthreads();
    }
    if (tid == 0) bsum[blockIdx.x] = sm[0];
}

__global__ void scanB_kernel(const int* __restrict__ bsum, int* __restrict__ boff,
                             int* __restrict__ rowptr, int B, int N) {
    __shared__ int sm[1024];
    int tid = threadIdx.x;
    int v = (tid < B) ? bsum[tid] : 0;
    sm[tid] = v;
    __syncthreads();
    for (int off = 1; off < 1024; off <<= 1) {
        int add = (tid >= off) ? sm[tid - off] : 0;
        __syncthreads();
        sm[tid] += add;
        __syncthreads();
    }
    if (tid < B) boff[tid] = sm[tid] - v;
    if (tid == 1023) rowptr[N] = sm[1023];
}

__global__ void scanC_kernel(const int* __restrict__ cnt, const int* __restrict__ boff,
                             int* __restrict__ rowptr, int N) {
    __shared__ int sm[256];
    int tid = threadIdx.x;
    int base = blockIdx.x * 1024 + tid * 4;
    int v[4];
    int s = 0;
#pragma unroll
    for (int i = 0; i < 4; ++i) {
        int idx = base + i;
        v[i] = (idx < N) ? cnt[idx] : 0;
        s += v[i];
    }
    sm[tid] = s;
    __syncthreads();
    for (int off = 1; off < 256; off <<= 1) {
        int add = (tid >= off) ? sm[tid - off] : 0;
        __syncthreads();
        sm[tid] += add;
        __syncthreads();
    }
    int run = boff[blockIdx.x] + sm[tid] - s;
#pragma unroll
    for (int i = 0; i < 4; ++i) {
        int idx = base + i;
        if (idx < N) rowptr[idx] = run;
        run += v[i];
    }
}

// gcur[b] = rowptr[b*256]  (bucket b's reserved base in `sorted`)
__global__ void gcinit_kernel(const int* __restrict__ rowptr, int* __restrict__ gcur, int NB) {
    int t = threadIdx.x;
    if (t < NB) gcur[t] = rowptr[t << 8];
}

// ---------------- S1: bucket scatter (counting-sort pass 1) ----------------
// Each block bins S1_CHUNK edges by bucket = dest>>8 in LDS, then writes
// lane-consecutive runs to each bucket's atomically reserved range in `sorted`.
// sorted entry is PACKED: (src << 8) | (dest & 255)  — bucket implied by range.
// LDS: 32KB ebuf + 8KB aux + 1KB scan = 41KB.

#define S1_CHUNK 4096
#define NB_MAX 512  // supports N <= 131072

__global__ __launch_bounds__(256) void s1_bucket(const int* __restrict__ row,
                                                 const int* __restrict__ col,
                                                 int* __restrict__ gcur,
                                                 int* __restrict__ sorted, int E, int NB) {
    __shared__ int2 ebuf[S1_CHUNK];      // 32KB
    __shared__ int cntL[NB_MAX];
    __shared__ int baseL[NB_MAX];
    __shared__ int curL[NB_MAX];
    __shared__ int gbaseL[NB_MAX];
    __shared__ int sm[256];
    int tid = threadIdx.x;
    int jb = blockIdx.x * S1_CHUNK;
    int je = min(jb + S1_CHUNK, E);
    int cntTot = je - jb;

    for (int t = tid; t < NB; t += 256) cntL[t] = 0;
    __syncthreads();
    // pass A: bucket counts
    for (int j = jb + tid; j < je; j += 256) atomicAdd(&cntL[col[j] >> 8], 1);
    __syncthreads();
    // exclusive scan of cntL[0..NB)
    int per = (NB + 255) >> 8;
    int s = 0;
    for (int q = 0; q < per; ++q) {
        int idx = tid * per + q;
        if (idx < NB) s += cntL[idx];
    }
    sm[tid] = s;
    __syncthreads();
    for (int off = 1; off < 256; off <<= 1) {
        int add = (tid >= off) ? sm[tid - off] : 0;
        __syncthreads();
        sm[tid] += add;
        __syncthreads();
    }
    int run = sm[tid] - s;
    for (int q = 0; q < per; ++q) {
        int idx = tid * per + q;
        if (idx < NB) { baseL[idx] = run; curL[idx] = run; run += cntL[idx]; }
    }
    __syncthreads();
    // reserve global ranges
    for (int t = tid; t < NB; t += 256)
        gbaseL[t] = atomicAdd(&gcur[t], cntL[t]);
    // pass B: place edges into LDS grouped by bucket
    for (int j = jb + tid; j < je; j += 256) {
        int c = col[j];
        int pos = atomicAdd(&curL[c >> 8], 1);
        ebuf[pos] = make_int2(row[j], c);
    }
    __syncthreads();
    // copy-out: consecutive LDS slots within a bucket -> consecutive global, packed
    for (int jj = tid; jj < cntTot; jj += 256) {
        int2 e = ebuf[jj];
        int t = e.y >> 8;
        sorted[gbaseL[t] + (jj - baseL[t])] = (e.x << 8) | (e.y & 255);
    }
}

// ---------------- S2: within-bucket CSR build ----------------
// Block b handles nodes [b*256,...); its edges are sorted[rowptr[b*256]..).
// Scatter confined to a 32KB sw region -> full L2 line merging.
// NOTE: rowL load MUST be a strided loop — nLoc can be 256 and rowL[256]
// (the bucket's end pointer) is loaded by thread 0's second iteration.
// A plain `if (tid <= nLoc)` leaves rowL[256] UNINITIALIZED (tid max 255):
// that was the OOB crash in rounds 4-8.

__global__ __launch_bounds__(256) void s2_csr(const int* __restrict__ sorted,
                                              const int* __restrict__ rowptr,
                                              const float* __restrict__ dinv,
                                              int2* __restrict__ sw, int N) {
    __shared__ int rowL[257];
    __shared__ int curL[256];
    __shared__ float dinvL[256];
    int tid = threadIdx.x;
    int c0 = blockIdx.x << 8;
    int nLoc = min(256, N - c0);
    for (int t = tid; t <= nLoc; t += 256) rowL[t] = rowptr[c0 + t];
    if (tid < nLoc) { curL[tid] = 0; dinvL[tid] = dinv[c0 + tid]; }
    __syncthreads();
    int gs = rowL[0], ge = rowL[nLoc];
    for (int j = gs + tid; j < ge; j += 256) {
        int e = sorted[j];
        int src = e >> 8;
        int cl = e & 255;
        int p = rowL[cl] + atomicAdd(&curL[cl], 1);
        float wv = dinv[src] * dinvL[cl];
        sw[p] = make_int2(src, __float_as_int(wv));
    }
}

// ---------------- f32 -> bf16 row conversion ----------------

__global__ void cvt_kernel(const float* __restrict__ x, unsigned short* __restrict__ xb,
                           int n4) {
    int i = blockIdx.x * blockDim.x + threadIdx.x;
    if (i >= n4) return;
    float4 v = *(const float4*)&x[(size_t)i * 4];
    ushort4 o;
    o.x = f2bf(v.x); o.y = f2bf(v.y); o.z = f2bf(v.z); o.w = f2bf(v.w);
    *(ushort4*)&xb[(size_t)i * 4] = o;
}

// ---------------- propagation ----------------
// One wave per node; 8 groups of 8 lanes; group g handles edges beg+g, beg+g+8,...
// Each lane loads 16B (8 bf16 features) -> 8 edges in flight per wave.
// f32 accumulate, bf16 output.

__global__ __launch_bounds__(256) void prop_kernel(const int* __restrict__ rowptr,
                                                   const int2* __restrict__ sw,
                                                   const unsigned short* __restrict__ hb,
                                                   unsigned short* __restrict__ outb, int N) {
    int gid = blockIdx.x * blockDim.x + threadIdx.x;
    int node = gid >> 6;
    if (node >= N) return;
    int lane = threadIdx.x & 63;
    int g = lane >> 3, l = lane & 7;
    int beg = rowptr[node], end = rowptr[node + 1];
    float a[8] = {};
    for (int j = beg + g; j < end; j += 8) {
        int2 e = sw[j];
        float ww = __int_as_float(e.y);
        us8 hv = *(const us8*)&hb[(size_t)e.x * DIN + l * 8];
#pragma unroll
        for (int k = 0; k < 8; ++k) a[k] = fmaf(ww, bf2f(hv[k]), a[k]);
    }
#pragma unroll
    for (int off = 8; off < 64; off <<= 1) {
#pragma unroll
        for (int k = 0; k < 8; ++k) a[k] += __shfl_xor(a[k], off, 64);
    }
    if (g == 0) {
        us8 o;
#pragma unroll
        for (int k = 0; k < 8; ++k) o[k] = f2bf(a[k]);
        *(us8*)&outb[(size_t)node * DIN + l * 8] = o;
    }
}

// ---------------- dense matmuls (H inputs bf16, W/accum f32) ----------------

__device__ __forceinline__ void stage_h(const unsigned short* __restrict__ hb,
                                        float (*Hs)[DIN + 1], int row0, int N, int tid) {
    for (int i = tid; i < 64 * 8; i += 256) {
        int r = i >> 3, k8 = (i & 7) * 8;
        int gr = row0 + r;
        if (gr < N) {
            us8 v = *(const us8*)&hb[(size_t)gr * DIN + k8];
#pragma unroll
            for (int k = 0; k < 8; ++k) Hs[r][k8 + k] = bf2f(v[k]);
        } else {
#pragma unroll
            for (int k = 0; k < 8; ++k) Hs[r][k8 + k] = 0.0f;
        }
    }
}

// mm3: out[N x DOUT] = h0@W[0] + h1@W[1] + h2@W[2]   (f32 out)
template <int DOUT>
__global__ __launch_bounds__(256) void mm3_kernel(const unsigned short* __restrict__ h0,
                                                  const unsigned short* __restrict__ h1,
                                                  const unsigned short* __restrict__ h2,
                                                  const float* __restrict__ W,
                                                  float* __restrict__ out, int N) {
    __shared__ float Ws[DIN][DOUT];
    __shared__ float Hs[64][DIN + 1];
    const unsigned short* hp[3] = {h0, h1, h2};
    int tid = threadIdx.x;
    int row0 = blockIdx.x * 64;
    constexpr int CT = DOUT / 4;
    int r0 = (tid / CT) * 4, c0 = (tid % CT) * 4;
    float a[4][4] = {};
#pragma unroll
    for (int kk = 0; kk < 3; ++kk) {
        for (int i = tid; i < DIN * DOUT; i += 256) Ws[i / DOUT][i % DOUT] = W[kk * DIN * DOUT + i];
        stage_h(hp[kk], Hs, row0, N, tid);
        __syncthreads();
        if (tid < 16 * CT) {
#pragma unroll
            for (int k = 0; k < DIN; ++k) {
                float b0 = Ws[k][c0 + 0], b1 = Ws[k][c0 + 1], b2 = Ws[k][c0 + 2], b3 = Ws[k][c0 + 3];
                float q0 = Hs[r0 + 0][k], q1 = Hs[r0 + 1][k], q2 = Hs[r0 + 2][k], q3 = Hs[r0 + 3][k];
                a[0][0] = fmaf(q0, b0, a[0][0]); a[0][1] = fmaf(q0, b1, a[0][1]);
                a[0][2] = fmaf(q0, b2, a[0][2]); a[0][3] = fmaf(q0, b3, a[0][3]);
                a[1][0] = fmaf(q1, b0, a[1][0]); a[1][1] = fmaf(q1, b1, a[1][1]);
                a[1][2] = fmaf(q1, b2, a[1][2]); a[1][3] = fmaf(q1, b3, a[1][3]);
                a[2][0] = fmaf(q2, b0, a[2][0]); a[2][1] = fmaf(q2, b1, a[2][1]);
                a[2][2] = fmaf(q2, b2, a[2][2]); a[2][3] = fmaf(q2, b3, a[2][3]);
                a[3][0] = fmaf(q3, b0, a[3][0]); a[3][1] = fmaf(q3, b1, a[3][1]);
                a[3][2] = fmaf(q3, b2, a[3][2]); a[3][3] = fmaf(q3, b3, a[3][3]);
            }
        }
        __syncthreads();
    }
    if (tid >= 16 * CT) return;
#pragma unroll
    for (int i = 0; i < 4; ++i) {
        int gr = row0 + r0 + i;
        if (gr >= N) continue;
#pragma unroll
        for (int c = 0; c < 4; ++c) out[(size_t)gr * DOUT + c0 + c] = a[i][c];
    }
}

// mm MODE 1: out_f32 = accin + H@W
// mm MODE 2: outb_bf16 = relu(accin + H@W + bias)
template <int DOUT, int MODE>
__global__ __launch_bounds__(256) void mm_kernel(const unsigned short* __restrict__ Hb,
                                                 const float* __restrict__ W,
                                                 const float* __restrict__ bias,
                                                 const float* __restrict__ accin,
                                                 float* __restrict__ out,
                                                 unsigned short* __restrict__ outb, int N) {
    __shared__ float Ws[DIN][DOUT];
    __shared__ float Hs[64][DIN + 1];
    int tid = threadIdx.x;
    int row0 = blockIdx.x * 64;
    for (int i = tid; i < DIN * DOUT; i += 256) Ws[i / DOUT][i % DOUT] = W[i];
    stage_h(Hb, Hs, row0, N, tid);
    __syncthreads();
    constexpr int CT = DOUT / 4;
    if (tid >= 16 * CT) return;
    int r0 = (tid / CT) * 4, c0 = (tid % CT) * 4;
    float a[4][4] = {};
#pragma unroll
    for (int k = 0; k < DIN; ++k) {
        float b0 = Ws[k][c0 + 0], b1 = Ws[k][c0 + 1], b2 = Ws[k][c0 + 2], b3 = Ws[k][c0 + 3];
        float q0 = Hs[r0 + 0][k], q1 = Hs[r0 + 1][k], q2 = Hs[r0 + 2][k], q3 = Hs[r0 + 3][k];
        a[0][0] = fmaf(q0, b0, a[0][0]); a[0][1] = fmaf(q0, b1, a[0][1]);
        a[0][2] = fmaf(q0, b2, a[0][2]); a[0][3] = fmaf(q0, b3, a[0][3]);
        a[1][0] = fmaf(q1, b0, a[1][0]); a[1][1] = fmaf(q1, b1, a[1][1]);
        a[1][2] = fmaf(q1, b2, a[1][2]); a[1][3] = fmaf(q1, b3, a[1][3]);
        a[2][0] = fmaf(q2, b0, a[2][0]); a[2][1] = fmaf(q2, b1, a[2][1]);
        a[2][2] = fmaf(q2, b2, a[2][2]); a[2][3] = fmaf(q2, b3, a[2][3]);
        a[3][0] = fmaf(q3, b0, a[3][0]); a[3][1] = fmaf(q3, b1, a[3][1]);
        a[3][2] = fmaf(q3, b2, a[3][2]); a[3][3] = fmaf(q3, b3, a[3][3]);
    }
#pragma unroll
    for (int i = 0; i < 4; ++i) {
        int gr = row0 + r0 + i;
        if (gr >= N) continue;
        float v[4];
#pragma unroll
        for (int c = 0; c < 4; ++c) {
            size_t o = (size_t)gr * DOUT + c0 + c;
            if (MODE == 1) {
                out[o] = accin[o] + a[i][c];
            } else {
                v[c] = accin[o] + a[i][c] + bias[c0 + c];
                v[c] = v[c] > 0.0f ? v[c] : 0.0f;
            }
        }
        if (MODE == 2) {
            ushort4 ob;
            ob.x = f2bf(v[0]); ob.y = f2bf(v[1]); ob.z = f2bf(v[2]); ob.w = f2bf(v[3]);
            *(ushort4*)&outb[(size_t)gr * DOUT + c0] = ob;
        }
    }
}

// ---------------- log_softmax over rows of 40 (one wave per row) ----------------

__global__ void lsm_kernel(float* __restrict__ out, const float* __restrict__ bias, int N) {
    int gid = blockIdx.x * blockDim.x + threadIdx.x;
    int row = gid >> 6;
    int lane = gid & 63;
    if (row >= N) return;
    float v = (lane < 40) ? out[(size_t)row * 40 + lane] + bias[lane] : -INFINITY;
    float m = v;
    for (int off = 32; off > 0; off >>= 1) m = fmaxf(m, __shfl_xor(m, off, 64));
    float e = (lane < 40) ? expf(v - m) : 0.0f;
    float ssum = e;
    for (int off = 32; off > 0; off >>= 1) ssum += __shfl_xor(ssum, off, 64);
    if (lane < 40) out[(size_t)row * 40 + lane] = v - m - logf(ssum);
}

// ---------------- launch ----------------

extern "C" void kernel_launch(void* const* d_in, const int* in_sizes, int n_in,
                              void* d_out, int out_size, void* d_ws, size_t ws_size,
                              hipStream_t stream) {
    const float* x  = (const float*)d_in[0];
    const int*   ei = (const int*)d_in[1];
    const float* W1 = (const float*)d_in[2];
    const float* b1 = (const float*)d_in[3];
    const float* W2 = (const float*)d_in[4];
    const float* b2 = (const float*)d_in[5];

    int N = in_sizes[0] / DIN;
    int E = in_sizes[1] / 2;
    const int* rowv = ei;       // edge_index[0] = message source
    const int* colv = ei + E;   // edge_index[1] = destination (segment id)
    int NB = (N + 255) >> 8;    // buckets of 256 nodes

    char* p = (char*)d_ws;
    auto alloc = [&](size_t bytes) {
        char* q = p;
        p += (bytes + 255) & ~(size_t)255;
        return q;
    };
    int*   cnt    = (int*)alloc((size_t)N * 4);
    int*   rowptr = (int*)alloc((size_t)(N + 1) * 4);
    float* dinv   = (float*)alloc((size_t)N * 4);
    int*   bsum   = (int*)alloc(1024 * 4);
    int*   boff   = (int*)alloc(1024 * 4);
    int*   gcur   = (int*)alloc(1024 * 4);
    int*   sorted = (int*)alloc((size_t)E * 4);
    int2*  sw     = (int2*)alloc((size_t)E * 8);
    float* acc    = (float*)alloc((size_t)N * DIN * 4);
    unsigned short* bfA = (unsigned short*)alloc((size_t)N * DIN * 2);
    unsigned short* bfB = (unsigned short*)alloc((size_t)N * DIN * 2);
    unsigned short* bfC = (unsigned short*)alloc((size_t)N * DIN * 2);
    unsigned short* bfD = (unsigned short*)alloc((size_t)N * DIN * 2);
    float* outp   = (float*)d_out;

    hipMemsetAsync(cnt, 0, (size_t)N * 4, stream);

    const int tpb = 256;
    int B = (N + 1023) / 1024;

    hist_kernel<<<1024, tpb, 0, stream>>>(colv, cnt, E);
    dinv_kernel<<<(N + tpb - 1) / tpb, tpb, 0, stream>>>(cnt, dinv, N);
    scanA_kernel<<<B, 256, 0, stream>>>(cnt, bsum, N);
    scanB_kernel<<<1, 1024, 0, stream>>>(bsum, boff, rowptr, B, N);
    scanC_kernel<<<B, 256, 0, stream>>>(cnt, boff, rowptr, N);
    gcinit_kernel<<<1, 1024, 0, stream>>>(rowptr, gcur, NB);
    s1_bucket<<<(E + S1_CHUNK - 1) / S1_CHUNK, 256, 0, stream>>>(rowv, colv, gcur, sorted, E, NB);
    s2_csr<<<NB, 256, 0, stream>>>(sorted, rowptr, dinv, sw, N);

    int propBlocks = (N * 64 + tpb - 1) / tpb;  // one wave per node
    int mmBlocks = (N + 63) / 64;
    int n4 = N * DIN / 4;
    cvt_kernel<<<(n4 + tpb - 1) / tpb, tpb, 0, stream>>>(x, bfA, n4);

    // ---- layer 1: acc = x@W1[0]+h1@W1[1]+h2@W1[2]; h = relu(acc + h3@W1[3] + b1)
    prop_kernel<<<propBlocks, tpb, 0, stream>>>(rowptr, sw, bfA, bfB, N);  // h1 -> bfB
    prop_kernel<<<propBlocks, tpb, 0, stream>>>(rowptr, sw, bfB, bfC, N);  // h2 -> bfC
    mm3_kernel<64><<<mmBlocks, 256, 0, stream>>>(bfA, bfB, bfC, W1, acc, N);
    prop_kernel<<<propBlocks, tpb, 0, stream>>>(rowptr, sw, bfC, bfD, N);  // h3 -> bfD
    mm_kernel<64, 2><<<mmBlocks, 256, 0, stream>>>(bfD, W1 + 3 * 64 * 64, b1, acc, nullptr, bfB, N);  // h -> bfB

    // ---- layer 2: out = h@W2[0]+q1@W2[1]+q2@W2[2]+q3@W2[3]; b2 folded into lsm
    prop_kernel<<<propBlocks, tpb, 0, stream>>>(rowptr, sw, bfB, bfC, N);  // q1 -> bfC
    prop_kernel<<<propBlocks, tpb, 0, stream>>>(rowptr, sw, bfC, bfD, N);  // q2 -> bfD
    mm3_kernel<40><<<mmBlocks, 256, 0, stream>>>(bfB, bfC, bfD, W2, outp, N);
    prop_kernel<<<propBlocks, tpb, 0, stream>>>(rowptr, sw, bfD, bfA, N);  // q3 -> bfA
    mm_kernel<40, 1><<<mmBlocks, 256, 0, stream>>>(bfA, W2 + 3 * 64 * 40, nullptr, outp, outp, nullptr, N);

    lsm_kernel<<<propBlocks, tpb, 0, stream>>>(outp, b2, N);
}

// Round 10
// 484.753 us; speedup vs baseline: 3.3598x; 1.2378x over previous
//
#include <hip/hip_runtime.h>
#include <math.h>

#define DIN 64
#define NB_MAX 512   // buckets of 256 nodes: supports N <= 131072
#define S1_CHUNK 4096

typedef unsigned short us8 __attribute__((ext_vector_type(8)));

// ---------------- bf16 helpers (RNE) ----------------

__device__ __forceinline__ float bf2f(unsigned short u) {
    return __uint_as_float(((unsigned int)u) << 16);
}
__device__ __forceinline__ unsigned short f2bf(float f) {
    unsigned int u = __float_as_uint(f);
    return (unsigned short)((u + 0x7fffu + ((u >> 16) & 1u)) >> 16);
}

// ---------------- per-BUCKET histogram (LDS-privatized; replaces per-node hist) --------

__global__ __launch_bounds__(256) void bcount_kernel(const int* __restrict__ col,
                                                     int* __restrict__ bcnt, int E, int NB) {
    __shared__ int cntB[NB_MAX];
    for (int t = threadIdx.x; t < NB; t += 256) cntB[t] = 0;
    __syncthreads();
    int stride = gridDim.x * blockDim.x;
    for (int i = blockIdx.x * blockDim.x + threadIdx.x; i < E; i += stride)
        atomicAdd(&cntB[col[i] >> 8], 1);
    __syncthreads();
    for (int t = threadIdx.x; t < NB; t += 256) {
        int c = cntB[t];
        if (c) atomicAdd(&bcnt[t], c);
    }
}

// scan bucket counts -> bbase[NB+1], init gcur, rowptr[N]=E. One block, 512 thr.
__global__ void bscan_kernel(const int* __restrict__ bcnt, int* __restrict__ bbase,
                             int* __restrict__ gcur, int* __restrict__ rowptr,
                             int NB, int N, int E) {
    __shared__ int sm[512];
    int tid = threadIdx.x;
    int v = (tid < NB) ? bcnt[tid] : 0;
    sm[tid] = v;
    __syncthreads();
    for (int off = 1; off < 512; off <<= 1) {
        int add = (tid >= off) ? sm[tid - off] : 0;
        __syncthreads();
        sm[tid] += add;
        __syncthreads();
    }
    if (tid < NB) { int b = sm[tid] - v; bbase[tid] = b; gcur[tid] = b; }
    if (tid == NB - 1) bbase[NB] = sm[tid];
    if (tid == 0) rowptr[N] = E;
}

// ---------------- S1: bucket scatter ----------------
// Bins S1_CHUNK edges by bucket=dest>>8 in LDS, writes lane-consecutive runs to
// atomically reserved ranges. Entry PACKED: (src<<8)|(dest&255).

__global__ __launch_bounds__(256) void s1_bucket(const int* __restrict__ row,
                                                 const int* __restrict__ col,
                                                 int* __restrict__ gcur,
                                                 int* __restrict__ sorted, int E, int NB) {
    __shared__ int2 ebuf[S1_CHUNK];      // 32KB
    __shared__ int cntL[NB_MAX];
    __shared__ int baseL[NB_MAX];
    __shared__ int curL[NB_MAX];
    __shared__ int gbaseL[NB_MAX];
    __shared__ int sm[256];
    int tid = threadIdx.x;
    int jb = blockIdx.x * S1_CHUNK;
    int je = min(jb + S1_CHUNK, E);
    int cntTot = je - jb;

    for (int t = tid; t < NB; t += 256) cntL[t] = 0;
    __syncthreads();
    for (int j = jb + tid; j < je; j += 256) atomicAdd(&cntL[col[j] >> 8], 1);
    __syncthreads();
    int per = (NB + 255) >> 8;
    int s = 0;
    for (int q = 0; q < per; ++q) {
        int idx = tid * per + q;
        if (idx < NB) s += cntL[idx];
    }
    sm[tid] = s;
    __syncthreads();
    for (int off = 1; off < 256; off <<= 1) {
        int add = (tid >= off) ? sm[tid - off] : 0;
        __syncthreads();
        sm[tid] += add;
        __syncthreads();
    }
    int run = sm[tid] - s;
    for (int q = 0; q < per; ++q) {
        int idx = tid * per + q;
        if (idx < NB) { baseL[idx] = run; curL[idx] = run; run += cntL[idx]; }
    }
    __syncthreads();
    for (int t = tid; t < NB; t += 256)
        gbaseL[t] = atomicAdd(&gcur[t], cntL[t]);
    for (int j = jb + tid; j < je; j += 256) {
        int c = col[j];
        int pos = atomicAdd(&curL[c >> 8], 1);
        ebuf[pos] = make_int2(row[j], c);
    }
    __syncthreads();
    for (int jj = tid; jj < cntTot; jj += 256) {
        int2 e = ebuf[jj];
        int t = e.y >> 8;
        sorted[gbaseL[t] + (jj - baseL[t])] = (e.x << 8) | (e.y & 255);
    }
}

// ---------------- S2: per-bucket counts + rowptr + dinv/rdinv + src placement --------
// Pass 1: count per-node in LDS; scan; write rowptr/dinv/rdinv (coalesced).
// Pass 2: place src into srcarr (scatter confined to ~deg*256*4B region).
// No cross-block dependency (weights are factored into features).

__global__ __launch_bounds__(256) void s2_kernel(const int* __restrict__ sorted,
                                                 const int* __restrict__ bbase,
                                                 int* __restrict__ rowptr,
                                                 float* __restrict__ dinv,
                                                 float* __restrict__ rdinv,
                                                 int* __restrict__ srcarr, int N) {
    __shared__ int cntL[256], baseL[256], sm[256];
    int tid = threadIdx.x;
    int b = blockIdx.x;
    int c0 = b << 8;
    int nLoc = min(256, N - c0);
    int gs = bbase[b], ge = bbase[b + 1];
    cntL[tid] = 0;
    __syncthreads();
    for (int j = gs + tid; j < ge; j += 256)
        atomicAdd(&cntL[sorted[j] & 255], 1);
    __syncthreads();
    int c = cntL[tid];
    sm[tid] = c;
    __syncthreads();
    for (int off = 1; off < 256; off <<= 1) {
        int add = (tid >= off) ? sm[tid - off] : 0;
        __syncthreads();
        sm[tid] += add;
        __syncthreads();
    }
    int base = gs + sm[tid] - c;  // exclusive prefix + bucket base
    baseL[tid] = base;
    if (tid < nLoc) {
        rowptr[c0 + tid] = base;
        dinv[c0 + tid] = (c > 0) ? rsqrtf((float)c) : 0.0f;
        rdinv[c0 + tid] = (c > 0) ? sqrtf((float)c) : 0.0f;
    }
    cntL[tid] = 0;  // reuse as cursor
    __syncthreads();
    for (int j = gs + tid; j < ge; j += 256) {
        int e = sorted[j];
        int cl = e & 255;
        int p = baseL[cl] + atomicAdd(&cntL[cl], 1);
        srcarr[p] = e >> 8;
    }
}

// ---------------- cvt: x -> hb0 (bf16) and sb0 = dinv*x (scaled bf16) ----------------

__global__ void cvt_kernel(const float* __restrict__ x, const float* __restrict__ dinv,
                           unsigned short* __restrict__ hb0, unsigned short* __restrict__ sb0,
                           int n4) {  // n4 = N*16 float4-groups
    int i = blockIdx.x * blockDim.x + threadIdx.x;
    if (i >= n4) return;
    float d = dinv[i >> 4];
    float4 v = *(const float4*)&x[(size_t)i * 4];
    ushort4 h, s;
    h.x = f2bf(v.x); h.y = f2bf(v.y); h.z = f2bf(v.z); h.w = f2bf(v.w);
    s.x = f2bf(d * v.x); s.y = f2bf(d * v.y); s.z = f2bf(d * v.z); s.w = f2bf(d * v.w);
    *(ushort4*)&hb0[(size_t)i * 4] = h;
    *(ushort4*)&sb0[(size_t)i * 4] = s;
}

// ---------------- propagation (scaled features: pure gather-sum) ----------------
// One wave per node; 8 groups x 8 lanes; group g handles edges beg+g, beg+g+8,...
// sb_out = dinv[v]^2 * sum(sb_in[src]);  (h reconstructed at mm via rdinv)

__global__ __launch_bounds__(256) void prop_kernel(const int* __restrict__ rowptr,
                                                   const int* __restrict__ srcarr,
                                                   const float* __restrict__ dinv,
                                                   const unsigned short* __restrict__ sb_in,
                                                   unsigned short* __restrict__ sb_out, int N) {
    int gid = blockIdx.x * blockDim.x + threadIdx.x;
    int node = gid >> 6;
    if (node >= N) return;
    int lane = threadIdx.x & 63;
    int g = lane >> 3, l = lane & 7;
    int beg = rowptr[node], end = rowptr[node + 1];
    float a[8] = {};
    for (int j = beg + g; j < end; j += 8) {
        int src = srcarr[j];
        us8 hv = *(const us8*)&sb_in[(size_t)src * DIN + l * 8];
#pragma unroll
        for (int k = 0; k < 8; ++k) a[k] += bf2f(hv[k]);
    }
#pragma unroll
    for (int off = 8; off < 64; off <<= 1) {
#pragma unroll
        for (int k = 0; k < 8; ++k) a[k] += __shfl_xor(a[k], off, 64);
    }
    if (g == 0) {
        float d = dinv[node];
        float d2 = d * d;
        us8 o;
#pragma unroll
        for (int k = 0; k < 8; ++k) o[k] = f2bf(d2 * a[k]);
        *(us8*)&sb_out[(size_t)node * DIN + l * 8] = o;
    }
}

// ---------------- mm4: out = h0@W[0] + h1@W[1] + h2@W[2] + h3@W[3] ----------------
// h0 unscaled bf16; h1..h3 are scaled buffers, unscaled by rdinv[row] at staging.
// MODE 2: v=relu(out+bias); write hbE=f2bf(v) and sbE=f2bf(dinv*v).
// MODE 0: write f32 out (bias folded into lsm).

template <int DOUT, int MODE>
__global__ __launch_bounds__(256) void mm4_kernel(const unsigned short* __restrict__ h0,
                                                  const unsigned short* __restrict__ s1,
                                                  const unsigned short* __restrict__ s2,
                                                  const unsigned short* __restrict__ s3,
                                                  const float* __restrict__ rdinv,
                                                  const float* __restrict__ dinv,
                                                  const float* __restrict__ W,
                                                  const float* __restrict__ bias,
                                                  float* __restrict__ outf,
                                                  unsigned short* __restrict__ outh,
                                                  unsigned short* __restrict__ outs, int N) {
    __shared__ float Ws[DIN][DOUT];
    __shared__ float Hs[64][DIN + 1];
    const unsigned short* hp[4] = {h0, s1, s2, s3};
    int tid = threadIdx.x;
    int row0 = blockIdx.x * 64;
    constexpr int CT = DOUT / 4;
    int r0 = (tid / CT) * 4, c0 = (tid % CT) * 4;
    float a[4][4] = {};
#pragma unroll
    for (int kk = 0; kk < 4; ++kk) {
        for (int i = tid; i < DIN * DOUT; i += 256) Ws[i / DOUT][i % DOUT] = W[kk * DIN * DOUT + i];
        for (int i = tid; i < 64 * 8; i += 256) {
            int r = i >> 3, k8 = (i & 7) * 8;
            int gr = row0 + r;
            if (gr < N) {
                float sc = (kk == 0) ? 1.0f : rdinv[gr];
                us8 v = *(const us8*)&hp[kk][(size_t)gr * DIN + k8];
#pragma unroll
                for (int k = 0; k < 8; ++k) Hs[r][k8 + k] = bf2f(v[k]) * sc;
            } else {
#pragma unroll
                for (int k = 0; k < 8; ++k) Hs[r][k8 + k] = 0.0f;
            }
        }
        __syncthreads();
        if (tid < 16 * CT) {
#pragma unroll
            for (int k = 0; k < DIN; ++k) {
                float b0 = Ws[k][c0 + 0], b1 = Ws[k][c0 + 1], b2 = Ws[k][c0 + 2], b3 = Ws[k][c0 + 3];
                float q0 = Hs[r0 + 0][k], q1 = Hs[r0 + 1][k], q2 = Hs[r0 + 2][k], q3 = Hs[r0 + 3][k];
                a[0][0] = fmaf(q0, b0, a[0][0]); a[0][1] = fmaf(q0, b1, a[0][1]);
                a[0][2] = fmaf(q0, b2, a[0][2]); a[0][3] = fmaf(q0, b3, a[0][3]);
                a[1][0] = fmaf(q1, b0, a[1][0]); a[1][1] = fmaf(q1, b1, a[1][1]);
                a[1][2] = fmaf(q1, b2, a[1][2]); a[1][3] = fmaf(q1, b3, a[1][3]);
                a[2][0] = fmaf(q2, b0, a[2][0]); a[2][1] = fmaf(q2, b1, a[2][1]);
                a[2][2] = fmaf(q2, b2, a[2][2]); a[2][3] = fmaf(q2, b3, a[2][3]);
                a[3][0] = fmaf(q3, b0, a[3][0]); a[3][1] = fmaf(q3, b1, a[3][1]);
                a[3][2] = fmaf(q3, b2, a[3][2]); a[3][3] = fmaf(q3, b3, a[3][3]);
            }
        }
        __syncthreads();
    }
    if (tid >= 16 * CT) return;
#pragma unroll
    for (int i = 0; i < 4; ++i) {
        int gr = row0 + r0 + i;
        if (gr >= N) continue;
        if (MODE == 0) {
#pragma unroll
            for (int c = 0; c < 4; ++c) outf[(size_t)gr * DOUT + c0 + c] = a[i][c];
        } else {
            float d = dinv[gr];
            ushort4 oh, os;
            float v0 = a[i][0] + bias[c0 + 0]; v0 = v0 > 0.f ? v0 : 0.f;
            float v1 = a[i][1] + bias[c0 + 1]; v1 = v1 > 0.f ? v1 : 0.f;
            float v2 = a[i][2] + bias[c0 + 2]; v2 = v2 > 0.f ? v2 : 0.f;
            float v3 = a[i][3] + bias[c0 + 3]; v3 = v3 > 0.f ? v3 : 0.f;
            oh.x = f2bf(v0); oh.y = f2bf(v1); oh.z = f2bf(v2); oh.w = f2bf(v3);
            os.x = f2bf(d * v0); os.y = f2bf(d * v1); os.z = f2bf(d * v2); os.w = f2bf(d * v3);
            *(ushort4*)&outh[(size_t)gr * DOUT + c0] = oh;
            *(ushort4*)&outs[(size_t)gr * DOUT + c0] = os;
        }
    }
}

// ---------------- log_softmax over rows of 40 (one wave per row) ----------------

__global__ void lsm_kernel(float* __restrict__ out, const float* __restrict__ bias, int N) {
    int gid = blockIdx.x * blockDim.x + threadIdx.x;
    int row = gid >> 6;
    int lane = gid & 63;
    if (row >= N) return;
    float v = (lane < 40) ? out[(size_t)row * 40 + lane] + bias[lane] : -INFINITY;
    float m = v;
    for (int off = 32; off > 0; off >>= 1) m = fmaxf(m, __shfl_xor(m, off, 64));
    float e = (lane < 40) ? expf(v - m) : 0.0f;
    float ssum = e;
    for (int off = 32; off > 0; off >>= 1) ssum += __shfl_xor(ssum, off, 64);
    if (lane < 40) out[(size_t)row * 40 + lane] = v - m - logf(ssum);
}

// ---------------- launch ----------------

extern "C" void kernel_launch(void* const* d_in, const int* in_sizes, int n_in,
                              void* d_out, int out_size, void* d_ws, size_t ws_size,
                              hipStream_t stream) {
    const float* x  = (const float*)d_in[0];
    const int*   ei = (const int*)d_in[1];
    const float* W1 = (const float*)d_in[2];
    const float* b1 = (const float*)d_in[3];
    const float* W2 = (const float*)d_in[4];
    const float* b2 = (const float*)d_in[5];

    int N = in_sizes[0] / DIN;
    int E = in_sizes[1] / 2;
    const int* rowv = ei;       // edge_index[0] = message source
    const int* colv = ei + E;   // edge_index[1] = destination (segment id)
    int NB = (N + 255) >> 8;

    char* p = (char*)d_ws;
    auto alloc = [&](size_t bytes) {
        char* q = p;
        p += (bytes + 255) & ~(size_t)255;
        return q;
    };
    int*   bcnt   = (int*)alloc(NB_MAX * 4);
    int*   bbase  = (int*)alloc((NB_MAX + 1) * 4);
    int*   gcur   = (int*)alloc(NB_MAX * 4);
    int*   rowptr = (int*)alloc((size_t)(N + 1) * 4);
    float* dinv   = (float*)alloc((size_t)N * 4);
    float* rdinv  = (float*)alloc((size_t)N * 4);
    int*   sorted = (int*)alloc((size_t)E * 4);
    int*   srcarr = (int*)alloc((size_t)E * 4);
    unsigned short* hb0 = (unsigned short*)alloc((size_t)N * DIN * 2);
    unsigned short* hbE = (unsigned short*)alloc((size_t)N * DIN * 2);
    unsigned short* sbA = (unsigned short*)alloc((size_t)N * DIN * 2);
    unsigned short* sbB = (unsigned short*)alloc((size_t)N * DIN * 2);
    unsigned short* sbC = (unsigned short*)alloc((size_t)N * DIN * 2);
    unsigned short* sbD = (unsigned short*)alloc((size_t)N * DIN * 2);
    float* outp   = (float*)d_out;

    hipMemsetAsync(bcnt, 0, NB_MAX * 4, stream);

    const int tpb = 256;

    bcount_kernel<<<128, tpb, 0, stream>>>(colv, bcnt, E, NB);
    bscan_kernel<<<1, 512, 0, stream>>>(bcnt, bbase, gcur, rowptr, NB, N, E);
    s1_bucket<<<(E + S1_CHUNK - 1) / S1_CHUNK, 256, 0, stream>>>(rowv, colv, gcur, sorted, E, NB);
    s2_kernel<<<NB, 256, 0, stream>>>(sorted, bbase, rowptr, dinv, rdinv, srcarr, N);

    int propBlocks = (N * 64 + tpb - 1) / tpb;  // one wave per node
    int mmBlocks = (N + 63) / 64;
    int n4 = N * 16;
    cvt_kernel<<<(n4 + tpb - 1) / tpb, tpb, 0, stream>>>(x, dinv, hb0, sbA, n4);  // sbA = sb0

    // ---- layer 1
    prop_kernel<<<propBlocks, tpb, 0, stream>>>(rowptr, srcarr, dinv, sbA, sbB, N);  // sb1
    prop_kernel<<<propBlocks, tpb, 0, stream>>>(rowptr, srcarr, dinv, sbB, sbC, N);  // sb2
    prop_kernel<<<propBlocks, tpb, 0, stream>>>(rowptr, srcarr, dinv, sbC, sbD, N);  // sb3
    mm4_kernel<64, 2><<<mmBlocks, 256, 0, stream>>>(hb0, sbB, sbC, sbD, rdinv, dinv,
                                                    W1, b1, nullptr, hbE, sbA, N);   // h->hbE, dinv*h->sbA

    // ---- layer 2 (b2 folded into lsm)
    prop_kernel<<<propBlocks, tpb, 0, stream>>>(rowptr, srcarr, dinv, sbA, sbB, N);  // q1
    prop_kernel<<<propBlocks, tpb, 0, stream>>>(rowptr, srcarr, dinv, sbB, sbC, N);  // q2
    prop_kernel<<<propBlocks, tpb, 0, stream>>>(rowptr, srcarr, dinv, sbC, sbD, N);  // q3
    mm4_kernel<40, 0><<<mmBlocks, 256, 0, stream>>>(hbE, sbB, sbC, sbD, rdinv, dinv,
                                                    W2, nullptr, outp, nullptr, nullptr, N);

    lsm_kernel<<<propBlocks, tpb, 0, stream>>>(outp, b2, N);
}

// Round 11
// 406.534 us; speedup vs baseline: 4.0063x; 1.1924x over previous
//
#include <hip/hip_runtime.h>
#include <math.h>

#define DIN 64
#define NB_MAX 512   // buckets of 256 nodes: supports N <= 131072
#define S1_CHUNK 4096

typedef unsigned short us8 __attribute__((ext_vector_type(8)));
typedef short s16x8 __attribute__((ext_vector_type(8)));
typedef float f32x4 __attribute__((ext_vector_type(4)));

// ---------------- bf16 helpers (RNE) ----------------

__device__ __forceinline__ float bf2f(unsigned short u) {
    return __uint_as_float(((unsigned int)u) << 16);
}
__device__ __forceinline__ unsigned short f2bf(float f) {
    unsigned int u = __float_as_uint(f);
    return (unsigned short)((u + 0x7fffu + ((u >> 16) & 1u)) >> 16);
}

// ---------------- per-BUCKET histogram ----------------

__global__ __launch_bounds__(256) void bcount_kernel(const int* __restrict__ col,
                                                     int* __restrict__ bcnt, int E, int NB) {
    __shared__ int cntB[NB_MAX];
    for (int t = threadIdx.x; t < NB; t += 256) cntB[t] = 0;
    __syncthreads();
    int stride = gridDim.x * blockDim.x;
    for (int i = blockIdx.x * blockDim.x + threadIdx.x; i < E; i += stride)
        atomicAdd(&cntB[col[i] >> 8], 1);
    __syncthreads();
    for (int t = threadIdx.x; t < NB; t += 256) {
        int c = cntB[t];
        if (c) atomicAdd(&bcnt[t], c);
    }
}

__global__ void bscan_kernel(const int* __restrict__ bcnt, int* __restrict__ bbase,
                             int* __restrict__ gcur, int* __restrict__ rowptr,
                             int NB, int N, int E) {
    __shared__ int sm[512];
    int tid = threadIdx.x;
    int v = (tid < NB) ? bcnt[tid] : 0;
    sm[tid] = v;
    __syncthreads();
    for (int off = 1; off < 512; off <<= 1) {
        int add = (tid >= off) ? sm[tid - off] : 0;
        __syncthreads();
        sm[tid] += add;
        __syncthreads();
    }
    if (tid < NB) { int b = sm[tid] - v; bbase[tid] = b; gcur[tid] = b; }
    if (tid == NB - 1) bbase[NB] = sm[tid];
    if (tid == 0) rowptr[N] = E;
}

// ---------------- S1: bucket scatter (entry packed (src<<8)|(dest&255)) ----------------

__global__ __launch_bounds__(256) void s1_bucket(const int* __restrict__ row,
                                                 const int* __restrict__ col,
                                                 int* __restrict__ gcur,
                                                 int* __restrict__ sorted, int E, int NB) {
    __shared__ int2 ebuf[S1_CHUNK];      // 32KB
    __shared__ int cntL[NB_MAX];
    __shared__ int baseL[NB_MAX];
    __shared__ int curL[NB_MAX];
    __shared__ int gbaseL[NB_MAX];
    __shared__ int sm[256];
    int tid = threadIdx.x;
    int jb = blockIdx.x * S1_CHUNK;
    int je = min(jb + S1_CHUNK, E);
    int cntTot = je - jb;

    for (int t = tid; t < NB; t += 256) cntL[t] = 0;
    __syncthreads();
    for (int j = jb + tid; j < je; j += 256) atomicAdd(&cntL[col[j] >> 8], 1);
    __syncthreads();
    int per = (NB + 255) >> 8;
    int s = 0;
    for (int q = 0; q < per; ++q) {
        int idx = tid * per + q;
        if (idx < NB) s += cntL[idx];
    }
    sm[tid] = s;
    __syncthreads();
    for (int off = 1; off < 256; off <<= 1) {
        int add = (tid >= off) ? sm[tid - off] : 0;
        __syncthreads();
        sm[tid] += add;
        __syncthreads();
    }
    int run = sm[tid] - s;
    for (int q = 0; q < per; ++q) {
        int idx = tid * per + q;
        if (idx < NB) { baseL[idx] = run; curL[idx] = run; run += cntL[idx]; }
    }
    __syncthreads();
    for (int t = tid; t < NB; t += 256)
        gbaseL[t] = atomicAdd(&gcur[t], cntL[t]);
    for (int j = jb + tid; j < je; j += 256) {
        int c = col[j];
        int pos = atomicAdd(&curL[c >> 8], 1);
        ebuf[pos] = make_int2(row[j], c);
    }
    __syncthreads();
    for (int jj = tid; jj < cntTot; jj += 256) {
        int2 e = ebuf[jj];
        int t = e.y >> 8;
        sorted[gbaseL[t] + (jj - baseL[t])] = (e.x << 8) | (e.y & 255);
    }
}

// ---------------- S2: per-bucket counts + rowptr + dinv/rdinv + src placement --------

__global__ __launch_bounds__(256) void s2_kernel(const int* __restrict__ sorted,
                                                 const int* __restrict__ bbase,
                                                 int* __restrict__ rowptr,
                                                 float* __restrict__ dinv,
                                                 float* __restrict__ rdinv,
                                                 int* __restrict__ srcarr, int N) {
    __shared__ int cntL[256], baseL[256], sm[256];
    int tid = threadIdx.x;
    int b = blockIdx.x;
    int c0 = b << 8;
    int nLoc = min(256, N - c0);
    int gs = bbase[b], ge = bbase[b + 1];
    cntL[tid] = 0;
    __syncthreads();
    for (int j = gs + tid; j < ge; j += 256)
        atomicAdd(&cntL[sorted[j] & 255], 1);
    __syncthreads();
    int c = cntL[tid];
    sm[tid] = c;
    __syncthreads();
    for (int off = 1; off < 256; off <<= 1) {
        int add = (tid >= off) ? sm[tid - off] : 0;
        __syncthreads();
        sm[tid] += add;
        __syncthreads();
    }
    int base = gs + sm[tid] - c;
    baseL[tid] = base;
    if (tid < nLoc) {
        rowptr[c0 + tid] = base;
        dinv[c0 + tid] = (c > 0) ? rsqrtf((float)c) : 0.0f;
        rdinv[c0 + tid] = (c > 0) ? sqrtf((float)c) : 0.0f;
    }
    cntL[tid] = 0;  // reuse as cursor
    __syncthreads();
    for (int j = gs + tid; j < ge; j += 256) {
        int e = sorted[j];
        int cl = e & 255;
        int p = baseL[cl] + atomicAdd(&cntL[cl], 1);
        srcarr[p] = e >> 8;
    }
}

// ---------------- cvt: x -> hb0 (bf16) and sb0 = dinv*x ----------------

__global__ void cvt_kernel(const float* __restrict__ x, const float* __restrict__ dinv,
                           unsigned short* __restrict__ hb0, unsigned short* __restrict__ sb0,
                           int n4) {
    int i = blockIdx.x * blockDim.x + threadIdx.x;
    if (i >= n4) return;
    float d = dinv[i >> 4];
    float4 v = *(const float4*)&x[(size_t)i * 4];
    ushort4 h, s;
    h.x = f2bf(v.x); h.y = f2bf(v.y); h.z = f2bf(v.z); h.w = f2bf(v.w);
    s.x = f2bf(d * v.x); s.y = f2bf(d * v.y); s.z = f2bf(d * v.z); s.w = f2bf(d * v.w);
    *(ushort4*)&hb0[(size_t)i * 4] = h;
    *(ushort4*)&sb0[(size_t)i * 4] = s;
}

// ---------------- propagation (scaled features: pure gather-sum) ----------------

__global__ __launch_bounds__(256) void prop_kernel(const int* __restrict__ rowptr,
                                                   const int* __restrict__ srcarr,
                                                   const float* __restrict__ dinv,
                                                   const unsigned short* __restrict__ sb_in,
                                                   unsigned short* __restrict__ sb_out, int N) {
    int gid = blockIdx.x * blockDim.x + threadIdx.x;
    int node = gid >> 6;
    if (node >= N) return;
    int lane = threadIdx.x & 63;
    int g = lane >> 3, l = lane & 7;
    int beg = rowptr[node], end = rowptr[node + 1];
    float a[8] = {};
    for (int j = beg + g; j < end; j += 8) {
        int src = srcarr[j];
        us8 hv = *(const us8*)&sb_in[(size_t)src * DIN + l * 8];
#pragma unroll
        for (int k = 0; k < 8; ++k) a[k] += bf2f(hv[k]);
    }
#pragma unroll
    for (int off = 8; off < 64; off <<= 1) {
#pragma unroll
        for (int k = 0; k < 8; ++k) a[k] += __shfl_xor(a[k], off, 64);
    }
    if (g == 0) {
        float d = dinv[node];
        float d2 = d * d;
        us8 o;
#pragma unroll
        for (int k = 0; k < 8; ++k) o[k] = f2bf(d2 * a[k]);
        *(us8*)&sb_out[(size_t)node * DIN + l * 8] = o;
    }
}

// ---------------- W prep: f32 [4][64][DOUTsrc] -> bf16 MFMA B-fragments ----------------
// Wb[(((kk*2+ks)*CT + ct)*64 + lane)*8 + j] = bf16(W[kk][ks*32+(lane>>4)*8+j][ct*16+(lane&15)])
// (cols >= DOUTsrc zero-padded)

__global__ void wprep_kernel(const float* __restrict__ W, unsigned short* __restrict__ Wb,
                             int DOUTsrc, int CT) {
    int idx = blockIdx.x * blockDim.x + threadIdx.x;
    int total = 4 * 2 * CT * 64;
    if (idx >= total) return;
    int lane = idx & 63;
    int rest = idx >> 6;              // (kk*2+ks)*CT + ct
    int ct = rest % CT;
    int tmp = rest / CT;
    int ks = tmp & 1, kk = tmp >> 1;
    int colc = ct * 16 + (lane & 15);
    int k0 = ks * 32 + (lane >> 4) * 8;
    us8 ov;
#pragma unroll
    for (int j = 0; j < 8; ++j) {
        float v = (colc < DOUTsrc) ? W[(size_t)(kk * 64 + k0 + j) * DOUTsrc + colc] : 0.0f;
        ov[j] = f2bf(v);
    }
    *(us8*)&Wb[(size_t)idx * 8] = ov;
}

// ---------------- MFMA mm4: out = h0@W[0] + rdinv_row * sum_i s_i@W[i] ----------------
// 4 waves/block, wave = 16 rows x (CT*16) cols. A straight from global bf16; B from Wb.
// rdinv diagonal commutes with the matmul -> applied once in the epilogue.
// MFMA layouts (m89-verified): A row=lane&15,k=(lane>>4)*8+j; B col=lane&15 same k;
// C/D col=lane&15, row=(lane>>4)*4+reg.
// MODE 2 (CT=4): v=relu(.+bias); write hbE=bf16(v), sbE=bf16(dinv*v).
// MODE 0 (CT=3, DOUT=40 padded to 48): write f32 out (first 40 cols).

template <int CT, int MODE>
__global__ __launch_bounds__(256) void mm4m_kernel(const unsigned short* __restrict__ h0,
                                                   const unsigned short* __restrict__ s1,
                                                   const unsigned short* __restrict__ s2,
                                                   const unsigned short* __restrict__ s3,
                                                   const float* __restrict__ rdinv,
                                                   const float* __restrict__ dinv,
                                                   const unsigned short* __restrict__ Wb,
                                                   const float* __restrict__ bias,
                                                   float* __restrict__ outf,
                                                   unsigned short* __restrict__ outh,
                                                   unsigned short* __restrict__ outs, int N) {
    constexpr int LSTR = (MODE == 2) ? 68 : 52;  // f32 row stride: 16B-aligned, <=2-way banks
    __shared__ __align__(16) float Lds[64 * LSTR];
    int tid = threadIdx.x;
    int w = tid >> 6, lane = tid & 63;
    int row0 = blockIdx.x * 64 + w * 16;
    int arow = row0 + (lane & 15);
    bool aok = arow < N;
    size_t abase = (size_t)arow * DIN + ((lane >> 4) * 8);
    const unsigned short* hp[4] = {h0, s1, s2, s3};

    f32x4 acc0[CT] = {};
    f32x4 accS[CT] = {};
#pragma unroll
    for (int kk = 0; kk < 4; ++kk) {
        const unsigned short* hb = hp[kk];
#pragma unroll
        for (int ks = 0; ks < 2; ++ks) {
            s16x8 a = {};
            if (aok) a = *(const s16x8*)&hb[abase + ks * 32];
#pragma unroll
            for (int c = 0; c < CT; ++c) {
                s16x8 b = *(const s16x8*)&Wb[(size_t)(((kk * 2 + ks) * CT + c) * 64 + lane) * 8];
                if (kk == 0)
                    acc0[c] = __builtin_amdgcn_mfma_f32_16x16x32_bf16(a, b, acc0[c], 0, 0, 0);
                else
                    accS[c] = __builtin_amdgcn_mfma_f32_16x16x32_bf16(a, b, accS[c], 0, 0, 0);
            }
        }
    }
    // epilogue: combine diagonals + (bias,relu) in-register, bounce via LDS for vector stores
    int lcol = lane & 15;
    int lrow4 = (lane >> 4) * 4;
#pragma unroll
    for (int r = 0; r < 4; ++r) {
        int lr = lrow4 + r;
        int grow = row0 + lr;
        float rd = (grow < N) ? rdinv[grow] : 0.0f;
#pragma unroll
        for (int c = 0; c < CT; ++c) {
            float v = acc0[c][r] + rd * accS[c][r];
            if (MODE == 2) {
                v += bias[c * 16 + lcol];
                v = v > 0.0f ? v : 0.0f;
            }
            Lds[(w * 16 + lr) * LSTR + c * 16 + lcol] = v;
        }
    }
    __syncthreads();
    int rowsInBlk = min(64, N - blockIdx.x * 64);
    if (MODE == 2) {
        for (int idx = tid; idx < rowsInBlk * 8; idx += 256) {
            int r = idx >> 3, k8 = (idx & 7) * 8;
            int gr = blockIdx.x * 64 + r;
            float d = dinv[gr];
            us8 oh, os;
#pragma unroll
            for (int k = 0; k < 8; ++k) {
                float v = Lds[r * LSTR + k8 + k];
                oh[k] = f2bf(v);
                os[k] = f2bf(d * v);
            }
            *(us8*)&outh[(size_t)gr * DIN + k8] = oh;
            *(us8*)&outs[(size_t)gr * DIN + k8] = os;
        }
    } else {
        for (int idx = tid; idx < rowsInBlk * 10; idx += 256) {
            int r = idx / 10, c4 = idx - r * 10;
            int gr = blockIdx.x * 64 + r;
            float4 v = *(float4*)&Lds[r * LSTR + c4 * 4];
            *(float4*)&outf[(size_t)gr * 40 + c4 * 4] = v;
        }
    }
}

// ---------------- log_softmax over rows of 40 (one wave per row) ----------------

__global__ void lsm_kernel(float* __restrict__ out, const float* __restrict__ bias, int N) {
    int gid = blockIdx.x * blockDim.x + threadIdx.x;
    int row = gid >> 6;
    int lane = gid & 63;
    if (row >= N) return;
    float v = (lane < 40) ? out[(size_t)row * 40 + lane] + bias[lane] : -INFINITY;
    float m = v;
    for (int off = 32; off > 0; off >>= 1) m = fmaxf(m, __shfl_xor(m, off, 64));
    float e = (lane < 40) ? expf(v - m) : 0.0f;
    float ssum = e;
    for (int off = 32; off > 0; off >>= 1) ssum += __shfl_xor(ssum, off, 64);
    if (lane < 40) out[(size_t)row * 40 + lane] = v - m - logf(ssum);
}

// ---------------- launch ----------------

extern "C" void kernel_launch(void* const* d_in, const int* in_sizes, int n_in,
                              void* d_out, int out_size, void* d_ws, size_t ws_size,
                              hipStream_t stream) {
    const float* x  = (const float*)d_in[0];
    const int*   ei = (const int*)d_in[1];
    const float* W1 = (const float*)d_in[2];
    const float* b1 = (const float*)d_in[3];
    const float* W2 = (const float*)d_in[4];
    const float* b2 = (const float*)d_in[5];

    int N = in_sizes[0] / DIN;
    int E = in_sizes[1] / 2;
    const int* rowv = ei;       // edge_index[0] = message source
    const int* colv = ei + E;   // edge_index[1] = destination (segment id)
    int NB = (N + 255) >> 8;

    char* p = (char*)d_ws;
    auto alloc = [&](size_t bytes) {
        char* q = p;
        p += (bytes + 255) & ~(size_t)255;
        return q;
    };
    int*   bcnt   = (int*)alloc(NB_MAX * 4);
    int*   bbase  = (int*)alloc((NB_MAX + 1) * 4);
    int*   gcur   = (int*)alloc(NB_MAX * 4);
    int*   rowptr = (int*)alloc((size_t)(N + 1) * 4);
    float* dinv   = (float*)alloc((size_t)N * 4);
    float* rdinv  = (float*)alloc((size_t)N * 4);
    int*   sorted = (int*)alloc((size_t)E * 4);
    int*   srcarr = (int*)alloc((size_t)E * 4);
    unsigned short* Wb1 = (unsigned short*)alloc((size_t)4 * 2 * 4 * 64 * 8 * 2);
    unsigned short* Wb2 = (unsigned short*)alloc((size_t)4 * 2 * 3 * 64 * 8 * 2);
    unsigned short* hb0 = (unsigned short*)alloc((size_t)N * DIN * 2);
    unsigned short* hbE = (unsigned short*)alloc((size_t)N * DIN * 2);
    unsigned short* sbA = (unsigned short*)alloc((size_t)N * DIN * 2);
    unsigned short* sbB = (unsigned short*)alloc((size_t)N * DIN * 2);
    unsigned short* sbC = (unsigned short*)alloc((size_t)N * DIN * 2);
    unsigned short* sbD = (unsigned short*)alloc((size_t)N * DIN * 2);
    float* outp   = (float*)d_out;

    hipMemsetAsync(bcnt, 0, NB_MAX * 4, stream);

    const int tpb = 256;

    bcount_kernel<<<128, tpb, 0, stream>>>(colv, bcnt, E, NB);
    bscan_kernel<<<1, 512, 0, stream>>>(bcnt, bbase, gcur, rowptr, NB, N, E);
    s1_bucket<<<(E + S1_CHUNK - 1) / S1_CHUNK, 256, 0, stream>>>(rowv, colv, gcur, sorted, E, NB);
    s2_kernel<<<NB, 256, 0, stream>>>(sorted, bbase, rowptr, dinv, rdinv, srcarr, N);
    wprep_kernel<<<8, tpb, 0, stream>>>(W1, Wb1, 64, 4);
    wprep_kernel<<<6, tpb, 0, stream>>>(W2, Wb2, 40, 3);

    int propBlocks = (N * 64 + tpb - 1) / tpb;  // one wave per node
    int mmBlocks = (N + 63) / 64;
    int n4 = N * 16;
    cvt_kernel<<<(n4 + tpb - 1) / tpb, tpb, 0, stream>>>(x, dinv, hb0, sbA, n4);  // sbA = sb0

    // ---- layer 1
    prop_kernel<<<propBlocks, tpb, 0, stream>>>(rowptr, srcarr, dinv, sbA, sbB, N);  // sb1
    prop_kernel<<<propBlocks, tpb, 0, stream>>>(rowptr, srcarr, dinv, sbB, sbC, N);  // sb2
    prop_kernel<<<propBlocks, tpb, 0, stream>>>(rowptr, srcarr, dinv, sbC, sbD, N);  // sb3
    mm4m_kernel<4, 2><<<mmBlocks, 256, 0, stream>>>(hb0, sbB, sbC, sbD, rdinv, dinv,
                                                    Wb1, b1, nullptr, hbE, sbA, N);  // h->hbE, dinv*h->sbA

    // ---- layer 2 (b2 folded into lsm)
    prop_kernel<<<propBlocks, tpb, 0, stream>>>(rowptr, srcarr, dinv, sbA, sbB, N);  // q1
    prop_kernel<<<propBlocks, tpb, 0, stream>>>(rowptr, srcarr, dinv, sbB, sbC, N);  // q2
    prop_kernel<<<propBlocks, tpb, 0, stream>>>(rowptr, srcarr, dinv, sbC, sbD, N);  // q3
    mm4m_kernel<3, 0><<<mmBlocks, 256, 0, stream>>>(hbE, sbB, sbC, sbD, rdinv, dinv,
                                                    Wb2, nullptr, outp, nullptr, nullptr, N);

    lsm_kernel<<<propBlocks, tpb, 0, stream>>>(outp, b2, N);
}

// Round 13
// 393.134 us; speedup vs baseline: 4.1428x; 1.0341x over previous
//
#include <hip/hip_runtime.h>
#include <math.h>

#define DIN 64
#define NB_MAX 512   // buckets of 256 nodes: supports N <= 131072
#define S1_CHUNK 4096

typedef unsigned short us8 __attribute__((ext_vector_type(8)));
typedef short s16x8 __attribute__((ext_vector_type(8)));
typedef float f32x4 __attribute__((ext_vector_type(4)));

// ---------------- bf16 helpers (RNE) ----------------

__device__ __forceinline__ float bf2f(unsigned short u) {
    return __uint_as_float(((unsigned int)u) << 16);
}
__device__ __forceinline__ unsigned short f2bf(float f) {
    unsigned int u = __float_as_uint(f);
    return (unsigned short)((u + 0x7fffu + ((u >> 16) & 1u)) >> 16);
}

// ---------------- per-BUCKET histogram ----------------

__global__ __launch_bounds__(256) void bcount_kernel(const int* __restrict__ col,
                                                     int* __restrict__ bcnt, int E, int NB) {
    __shared__ int cntB[NB_MAX];
    for (int t = threadIdx.x; t < NB; t += 256) cntB[t] = 0;
    __syncthreads();
    int stride = gridDim.x * blockDim.x;
    for (int i = blockIdx.x * blockDim.x + threadIdx.x; i < E; i += stride)
        atomicAdd(&cntB[col[i] >> 8], 1);
    __syncthreads();
    for (int t = threadIdx.x; t < NB; t += 256) {
        int c = cntB[t];
        if (c) atomicAdd(&bcnt[t], c);
    }
}

__global__ void bscan_kernel(const int* __restrict__ bcnt, int* __restrict__ bbase,
                             int* __restrict__ gcur, int* __restrict__ rowptr,
                             int NB, int N, int E) {
    __shared__ int sm[512];
    int tid = threadIdx.x;
    int v = (tid < NB) ? bcnt[tid] : 0;
    sm[tid] = v;
    __syncthreads();
    for (int off = 1; off < 512; off <<= 1) {
        int add = (tid >= off) ? sm[tid - off] : 0;
        __syncthreads();
        sm[tid] += add;
        __syncthreads();
    }
    if (tid < NB) { int b = sm[tid] - v; bbase[tid] = b; gcur[tid] = b; }
    if (tid == NB - 1) bbase[NB] = sm[tid];
    if (tid == 0) rowptr[N] = E;
}

// ---------------- S1: bucket scatter (entry packed (src<<8)|(dest&255)) ----------------

__global__ __launch_bounds__(256) void s1_bucket(const int* __restrict__ row,
                                                 const int* __restrict__ col,
                                                 int* __restrict__ gcur,
                                                 int* __restrict__ sorted, int E, int NB) {
    __shared__ int2 ebuf[S1_CHUNK];      // 32KB
    __shared__ int cntL[NB_MAX];
    __shared__ int baseL[NB_MAX];
    __shared__ int curL[NB_MAX];
    __shared__ int gbaseL[NB_MAX];
    __shared__ int sm[256];
    int tid = threadIdx.x;
    int jb = blockIdx.x * S1_CHUNK;
    int je = min(jb + S1_CHUNK, E);
    int cntTot = je - jb;

    for (int t = tid; t < NB; t += 256) cntL[t] = 0;
    __syncthreads();
    for (int j = jb + tid; j < je; j += 256) atomicAdd(&cntL[col[j] >> 8], 1);
    __syncthreads();
    int per = (NB + 255) >> 8;
    int s = 0;
    for (int q = 0; q < per; ++q) {
        int idx = tid * per + q;
        if (idx < NB) s += cntL[idx];
    }
    sm[tid] = s;
    __syncthreads();
    for (int off = 1; off < 256; off <<= 1) {
        int add = (tid >= off) ? sm[tid - off] : 0;
        __syncthreads();
        sm[tid] += add;
        __syncthreads();
    }
    int run = sm[tid] - s;
    for (int q = 0; q < per; ++q) {
        int idx = tid * per + q;
        if (idx < NB) { baseL[idx] = run; curL[idx] = run; run += cntL[idx]; }
    }
    __syncthreads();
    for (int t = tid; t < NB; t += 256)
        gbaseL[t] = atomicAdd(&gcur[t], cntL[t]);
    for (int j = jb + tid; j < je; j += 256) {
        int c = col[j];
        int pos = atomicAdd(&curL[c >> 8], 1);
        ebuf[pos] = make_int2(row[j], c);
    }
    __syncthreads();
    for (int jj = tid; jj < cntTot; jj += 256) {
        int2 e = ebuf[jj];
        int t = e.y >> 8;
        sorted[gbaseL[t] + (jj - baseL[t])] = (e.x << 8) | (e.y & 255);
    }
}

// ---------------- S2: per-bucket counts + rowptr + dinv/rdinv + src placement --------

__global__ __launch_bounds__(256) void s2_kernel(const int* __restrict__ sorted,
                                                 const int* __restrict__ bbase,
                                                 int* __restrict__ rowptr,
                                                 float* __restrict__ dinv,
                                                 float* __restrict__ rdinv,
                                                 int* __restrict__ srcarr, int N) {
    __shared__ int cntL[256], baseL[256], sm[256];
    int tid = threadIdx.x;
    int b = blockIdx.x;
    int c0 = b << 8;
    int nLoc = min(256, N - c0);
    int gs = bbase[b], ge = bbase[b + 1];
    cntL[tid] = 0;
    __syncthreads();
    for (int j = gs + tid; j < ge; j += 256)
        atomicAdd(&cntL[sorted[j] & 255], 1);
    __syncthreads();
    int c = cntL[tid];
    sm[tid] = c;
    __syncthreads();
    for (int off = 1; off < 256; off <<= 1) {
        int add = (tid >= off) ? sm[tid - off] : 0;
        __syncthreads();
        sm[tid] += add;
        __syncthreads();
    }
    int base = gs + sm[tid] - c;
    baseL[tid] = base;
    if (tid < nLoc) {
        rowptr[c0 + tid] = base;
        dinv[c0 + tid] = (c > 0) ? rsqrtf((float)c) : 0.0f;
        rdinv[c0 + tid] = (c > 0) ? sqrtf((float)c) : 0.0f;
    }
    cntL[tid] = 0;  // reuse as cursor
    __syncthreads();
    for (int j = gs + tid; j < ge; j += 256) {
        int e = sorted[j];
        int cl = e & 255;
        int p = baseL[cl] + atomicAdd(&cntL[cl], 1);
        srcarr[p] = e >> 8;
    }
}

// ---------------- cvt: x -> hb0 (bf16) and sb0 = dinv*x ----------------

__global__ void cvt_kernel(const float* __restrict__ x, const float* __restrict__ dinv,
                           unsigned short* __restrict__ hb0, unsigned short* __restrict__ sb0,
                           int n4) {
    int i = blockIdx.x * blockDim.x + threadIdx.x;
    if (i >= n4) return;
    float d = dinv[i >> 4];
    float4 v = *(const float4*)&x[(size_t)i * 4];
    ushort4 h, s;
    h.x = f2bf(v.x); h.y = f2bf(v.y); h.z = f2bf(v.z); h.w = f2bf(v.w);
    s.x = f2bf(d * v.x); s.y = f2bf(d * v.y); s.z = f2bf(d * v.z); s.w = f2bf(d * v.w);
    *(ushort4*)&hb0[(size_t)i * 4] = h;
    *(ushort4*)&sb0[(size_t)i * 4] = s;
}

// ---------------- propagation (scaled features: pure gather-sum) ----------------
// One wave per node; 8 groups x 8 lanes. Edge list register-cached: the wave loads
// srcarr[beg+lane] once (coalesced); per-edge index via __shfl.
// CORRECTNESS: the broadcast loop bound is WAVE-UNIFORM (iters = ceil(lim/8)) so
// every lane executes every __shfl — a divergent per-group bound made source
// lanes exit before readers (undefined shfl) in round 11 (absmax 0.28 fail).
// Only the gather/accumulate is predicated (jj < lim).

__global__ __launch_bounds__(256) void prop_kernel(const int* __restrict__ rowptr,
                                                   const int* __restrict__ srcarr,
                                                   const float* __restrict__ dinv,
                                                   const unsigned short* __restrict__ sb_in,
                                                   unsigned short* __restrict__ sb_out, int N) {
    int gid = blockIdx.x * blockDim.x + threadIdx.x;
    int node = gid >> 6;
    if (node >= N) return;
    int lane = threadIdx.x & 63;
    int g = lane >> 3, l = lane & 7;
    int beg = rowptr[node], end = rowptr[node + 1];
    int deg = end - beg;
    float a[8] = {};
    for (int chunk = 0; chunk < deg; chunk += 64) {
        int lim = min(64, deg - chunk);           // wave-uniform
        int src_l = (lane < lim) ? srcarr[beg + chunk + lane] : 0;
        int iters = (lim + 7) >> 3;               // wave-uniform
        for (int t = 0; t < iters; ++t) {
            int jj = g + (t << 3);                // <= 63 always
            int src = __shfl(src_l, jj, 64);      // all 64 lanes active
            if (jj < lim) {
                us8 hv = *(const us8*)&sb_in[(size_t)src * DIN + l * 8];
#pragma unroll
                for (int k = 0; k < 8; ++k) a[k] += bf2f(hv[k]);
            }
        }
    }
#pragma unroll
    for (int off = 8; off < 64; off <<= 1) {
#pragma unroll
        for (int k = 0; k < 8; ++k) a[k] += __shfl_xor(a[k], off, 64);
    }
    if (g == 0) {
        float d = dinv[node];
        float d2 = d * d;
        us8 o;
#pragma unroll
        for (int k = 0; k < 8; ++k) o[k] = f2bf(d2 * a[k]);
        *(us8*)&sb_out[(size_t)node * DIN + l * 8] = o;
    }
}

// ---------------- W prep: f32 [4][64][DOUTsrc] -> bf16 MFMA B-fragments ----------------

__global__ void wprep_kernel(const float* __restrict__ W, unsigned short* __restrict__ Wb,
                             int DOUTsrc, int CT) {
    int idx = blockIdx.x * blockDim.x + threadIdx.x;
    int total = 4 * 2 * CT * 64;
    if (idx >= total) return;
    int lane = idx & 63;
    int rest = idx >> 6;              // (kk*2+ks)*CT + ct
    int ct = rest % CT;
    int tmp = rest / CT;
    int ks = tmp & 1, kk = tmp >> 1;
    int colc = ct * 16 + (lane & 15);
    int k0 = ks * 32 + (lane >> 4) * 8;
    us8 ov;
#pragma unroll
    for (int j = 0; j < 8; ++j) {
        float v = (colc < DOUTsrc) ? W[(size_t)(kk * 64 + k0 + j) * DOUTsrc + colc] : 0.0f;
        ov[j] = f2bf(v);
    }
    *(us8*)&Wb[(size_t)idx * 8] = ov;
}

// ---------------- MFMA mm4: out = h0@W[0] + rdinv_row * sum_i s_i@W[i] ----------------

template <int CT, int MODE>
__global__ __launch_bounds__(256) void mm4m_kernel(const unsigned short* __restrict__ h0,
                                                   const unsigned short* __restrict__ s1,
                                                   const unsigned short* __restrict__ s2,
                                                   const unsigned short* __restrict__ s3,
                                                   const float* __restrict__ rdinv,
                                                   const float* __restrict__ dinv,
                                                   const unsigned short* __restrict__ Wb,
                                                   const float* __restrict__ bias,
                                                   float* __restrict__ outf,
                                                   unsigned short* __restrict__ outh,
                                                   unsigned short* __restrict__ outs, int N) {
    constexpr int LSTR = (MODE == 2) ? 68 : 52;  // f32 row stride: 16B-aligned, <=2-way banks
    __shared__ __align__(16) float Lds[64 * LSTR];
    int tid = threadIdx.x;
    int w = tid >> 6, lane = tid & 63;
    int row0 = blockIdx.x * 64 + w * 16;
    int arow = row0 + (lane & 15);
    bool aok = arow < N;
    size_t abase = (size_t)arow * DIN + ((lane >> 4) * 8);
    const unsigned short* hp[4] = {h0, s1, s2, s3};

    f32x4 acc0[CT] = {};
    f32x4 accS[CT] = {};
#pragma unroll
    for (int kk = 0; kk < 4; ++kk) {
        const unsigned short* hb = hp[kk];
#pragma unroll
        for (int ks = 0; ks < 2; ++ks) {
            s16x8 a = {};
            if (aok) a = *(const s16x8*)&hb[abase + ks * 32];
#pragma unroll
            for (int c = 0; c < CT; ++c) {
                s16x8 b = *(const s16x8*)&Wb[(size_t)(((kk * 2 + ks) * CT + c) * 64 + lane) * 8];
                if (kk == 0)
                    acc0[c] = __builtin_amdgcn_mfma_f32_16x16x32_bf16(a, b, acc0[c], 0, 0, 0);
                else
                    accS[c] = __builtin_amdgcn_mfma_f32_16x16x32_bf16(a, b, accS[c], 0, 0, 0);
            }
        }
    }
    int lcol = lane & 15;
    int lrow4 = (lane >> 4) * 4;
#pragma unroll
    for (int r = 0; r < 4; ++r) {
        int lr = lrow4 + r;
        int grow = row0 + lr;
        float rd = (grow < N) ? rdinv[grow] : 0.0f;
#pragma unroll
        for (int c = 0; c < CT; ++c) {
            float v = acc0[c][r] + rd * accS[c][r];
            if (MODE == 2) {
                v += bias[c * 16 + lcol];
                v = v > 0.0f ? v : 0.0f;
            }
            Lds[(w * 16 + lr) * LSTR + c * 16 + lcol] = v;
        }
    }
    __syncthreads();
    int rowsInBlk = min(64, N - blockIdx.x * 64);
    if (MODE == 2) {
        for (int idx = tid; idx < rowsInBlk * 8; idx += 256) {
            int r = idx >> 3, k8 = (idx & 7) * 8;
            int gr = blockIdx.x * 64 + r;
            float d = dinv[gr];
            us8 oh, os;
#pragma unroll
            for (int k = 0; k < 8; ++k) {
                float v = Lds[r * LSTR + k8 + k];
                oh[k] = f2bf(v);
                os[k] = f2bf(d * v);
            }
            *(us8*)&outh[(size_t)gr * DIN + k8] = oh;
            *(us8*)&outs[(size_t)gr * DIN + k8] = os;
        }
    } else {
        for (int idx = tid; idx < rowsInBlk * 10; idx += 256) {
            int r = idx / 10, c4 = idx - r * 10;
            int gr = blockIdx.x * 64 + r;
            float4 v = *(float4*)&Lds[r * LSTR + c4 * 4];
            *(float4*)&outf[(size_t)gr * 40 + c4 * 4] = v;
        }
    }
}

// ---------------- log_softmax over rows of 40 (one wave per row) ----------------

__global__ void lsm_kernel(float* __restrict__ out, const float* __restrict__ bias, int N) {
    int gid = blockIdx.x * blockDim.x + threadIdx.x;
    int row = gid >> 6;
    int lane = gid & 63;
    if (row >= N) return;
    float v = (lane < 40) ? out[(size_t)row * 40 + lane] + bias[lane] : -INFINITY;
    float m = v;
    for (int off = 32; off > 0; off >>= 1) m = fmaxf(m, __shfl_xor(m, off, 64));
    float e = (lane < 40) ? expf(v - m) : 0.0f;
    float ssum = e;
    for (int off = 32; off > 0; off >>= 1) ssum += __shfl_xor(ssum, off, 64);
    if (lane < 40) out[(size_t)row * 40 + lane] = v - m - logf(ssum);
}

// ---------------- launch ----------------

extern "C" void kernel_launch(void* const* d_in, const int* in_sizes, int n_in,
                              void* d_out, int out_size, void* d_ws, size_t ws_size,
                              hipStream_t stream) {
    const float* x  = (const float*)d_in[0];
    const int*   ei = (const int*)d_in[1];
    const float* W1 = (const float*)d_in[2];
    const float* b1 = (const float*)d_in[3];
    const float* W2 = (const float*)d_in[4];
    const float* b2 = (const float*)d_in[5];

    int N = in_sizes[0] / DIN;
    int E = in_sizes[1] / 2;
    const int* rowv = ei;       // edge_index[0] = message source
    const int* colv = ei + E;   // edge_index[1] = destination (segment id)
    int NB = (N + 255) >> 8;

    char* p = (char*)d_ws;
    auto alloc = [&](size_t bytes) {
        char* q = p;
        p += (bytes + 255) & ~(size_t)255;
        return q;
    };
    int*   bcnt   = (int*)alloc(NB_MAX * 4);
    int*   bbase  = (int*)alloc((NB_MAX + 1) * 4);
    int*   gcur   = (int*)alloc(NB_MAX * 4);
    int*   rowptr = (int*)alloc((size_t)(N + 1) * 4);
    float* dinv   = (float*)alloc((size_t)N * 4);
    float* rdinv  = (float*)alloc((size_t)N * 4);
    int*   sorted = (int*)alloc((size_t)E * 4);
    int*   srcarr = (int*)alloc((size_t)E * 4);
    unsigned short* Wb1 = (unsigned short*)alloc((size_t)4 * 2 * 4 * 64 * 8 * 2);
    unsigned short* Wb2 = (unsigned short*)alloc((size_t)4 * 2 * 3 * 64 * 8 * 2);
    unsigned short* hb0 = (unsigned short*)alloc((size_t)N * DIN * 2);
    unsigned short* hbE = (unsigned short*)alloc((size_t)N * DIN * 2);
    unsigned short* sbA = (unsigned short*)alloc((size_t)N * DIN * 2);
    unsigned short* sbB = (unsigned short*)alloc((size_t)N * DIN * 2);
    unsigned short* sbC = (unsigned short*)alloc((size_t)N * DIN * 2);
    unsigned short* sbD = (unsigned short*)alloc((size_t)N * DIN * 2);
    float* outp   = (float*)d_out;

    hipMemsetAsync(bcnt, 0, NB_MAX * 4, stream);

    const int tpb = 256;

    bcount_kernel<<<128, tpb, 0, stream>>>(colv, bcnt, E, NB);
    bscan_kernel<<<1, 512, 0, stream>>>(bcnt, bbase, gcur, rowptr, NB, N, E);
    s1_bucket<<<(E + S1_CHUNK - 1) / S1_CHUNK, 256, 0, stream>>>(rowv, colv, gcur, sorted, E, NB);
    s2_kernel<<<NB, 256, 0, stream>>>(sorted, bbase, rowptr, dinv, rdinv, srcarr, N);
    wprep_kernel<<<8, tpb, 0, stream>>>(W1, Wb1, 64, 4);
    wprep_kernel<<<6, tpb, 0, stream>>>(W2, Wb2, 40, 3);

    int propBlocks = (N * 64 + tpb - 1) / tpb;  // one wave per node
    int mmBlocks = (N + 63) / 64;
    int n4 = N * 16;
    cvt_kernel<<<(n4 + tpb - 1) / tpb, tpb, 0, stream>>>(x, dinv, hb0, sbA, n4);  // sbA = sb0

    // ---- layer 1
    prop_kernel<<<propBlocks, tpb, 0, stream>>>(rowptr, srcarr, dinv, sbA, sbB, N);  // sb1
    prop_kernel<<<propBlocks, tpb, 0, stream>>>(rowptr, srcarr, dinv, sbB, sbC, N);  // sb2
    prop_kernel<<<propBlocks, tpb, 0, stream>>>(rowptr, srcarr, dinv, sbC, sbD, N);  // sb3
    mm4m_kernel<4, 2><<<mmBlocks, 256, 0, stream>>>(hb0, sbB, sbC, sbD, rdinv, dinv,
                                                    Wb1, b1, nullptr, hbE, sbA, N);  // h->hbE, dinv*h->sbA

    // ---- layer 2 (b2 folded into lsm)
    prop_kernel<<<propBlocks, tpb, 0, stream>>>(rowptr, srcarr, dinv, sbA, sbB, N);  // q1
    prop_kernel<<<propBlocks, tpb, 0, stream>>>(rowptr, srcarr, dinv, sbB, sbC, N);  // q2
    prop_kernel<<<propBlocks, tpb, 0, stream>>>(rowptr, srcarr, dinv, sbC, sbD, N);  // q3
    mm4m_kernel<3, 0><<<mmBlocks, 256, 0, stream>>>(hbE, sbB, sbC, sbD, rdinv, dinv,
                                                    Wb2, nullptr, outp, nullptr, nullptr, N);

    lsm_kernel<<<propBlocks, tpb, 0, stream>>>(outp, b2, N);
}